// Round 2
// baseline (539.274 us; speedup 1.0000x reference)
//
#include <hip/hip_runtime.h>

#define D 128
#define LEAKY 0.01f
#define SCAN_CHUNK 2048   // 256 threads x 8 elements

// ---------------- edge preprocessing ----------------

__global__ void k_edge_rowsum(const int* __restrict__ src, const float* __restrict__ w,
                              float* __restrict__ rowsum, int E) {
    int e = blockIdx.x * 256 + threadIdx.x;
    if (e < E) atomicAdd(&rowsum[src[e]], w[e]);
}

__global__ void k_edge_deg(const int* __restrict__ src, const int* __restrict__ dst,
                           const float* __restrict__ w, const float* __restrict__ rowsum,
                           float* __restrict__ deg, int* __restrict__ cnt, int E) {
    int e = blockIdx.x * 256 + threadIdx.x;
    if (e >= E) return;
    int s = src[e], d = dst[e];
    float rs = rowsum[s], rd = rowsum[d];
    float wh = w[e] * (rs > 0.f ? 1.f / rs : 0.f) * (rd > 0.f ? 1.f / rd : 0.f);
    atomicAdd(&deg[d], wh);
    atomicAdd(&cnt[d], 1);
}

// ---------------- prefix scan (3-phase) over cnt[N] -> start[N+1] ----------------

__global__ void k_chunk_sum(const int* __restrict__ cnt, int* __restrict__ partial, int n) {
    __shared__ int sdata[256];
    int b = blockIdx.x;
    int base = b * SCAN_CHUNK;
    int s = 0;
    for (int i = threadIdx.x; i < SCAN_CHUNK; i += 256) {
        int idx = base + i;
        s += (idx < n) ? cnt[idx] : 0;
    }
    sdata[threadIdx.x] = s;
    __syncthreads();
    for (int off = 128; off > 0; off >>= 1) {
        if (threadIdx.x < off) sdata[threadIdx.x] += sdata[threadIdx.x + off];
        __syncthreads();
    }
    if (threadIdx.x == 0) partial[b] = sdata[0];
}

__global__ void k_scan_partial(int* __restrict__ partial, int nchunks) {
    if (blockIdx.x == 0 && threadIdx.x == 0) {
        int run = 0;
        for (int i = 0; i < nchunks; i++) { int v = partial[i]; partial[i] = run; run += v; }
    }
}

__global__ void k_chunk_scan(const int* __restrict__ cnt, const int* __restrict__ partial,
                             int* __restrict__ start, int n, int total) {
    __shared__ int sdata[256];
    int b = blockIdx.x;
    int base = b * SCAN_CHUNK;
    int t = threadIdx.x;
    int loc[8];
    int s = 0;
    int tb = base + t * 8;
    #pragma unroll
    for (int j = 0; j < 8; j++) {
        int idx = tb + j;
        int v = (idx < n) ? cnt[idx] : 0;
        loc[j] = s;
        s += v;
    }
    sdata[t] = s;
    __syncthreads();
    for (int off = 1; off < 256; off <<= 1) {
        int v = (t >= off) ? sdata[t - off] : 0;
        __syncthreads();
        sdata[t] += v;
        __syncthreads();
    }
    int texcl = (t == 0) ? 0 : sdata[t - 1];
    int offb = partial[b];
    #pragma unroll
    for (int j = 0; j < 8; j++) {
        int idx = tb + j;
        if (idx < n) start[idx] = offb + texcl + loc[j];
    }
    if (b == gridDim.x - 1 && t == 255) start[n] = total;
}

// fused: recompute w_hat, apply symmetric norm, scatter into dst-CSR
__global__ void k_scatter_norm(const int* __restrict__ src, const int* __restrict__ dst,
                               const float* __restrict__ w, const float* __restrict__ rowsum,
                               const float* __restrict__ deg, const int* __restrict__ start,
                               int* __restrict__ cursor, int* __restrict__ csr_src,
                               float* __restrict__ csr_norm, int E) {
    int e = blockIdx.x * 256 + threadIdx.x;
    if (e >= E) return;
    int s = src[e], d = dst[e];
    float rs = rowsum[s], rd = rowsum[d];
    float wh = w[e] * (rs > 0.f ? 1.f / rs : 0.f) * (rd > 0.f ? 1.f / rd : 0.f);
    float ds = deg[s], dd = deg[d];
    float nm = wh * (ds > 0.f ? rsqrtf(ds) : 0.f) * (dd > 0.f ? rsqrtf(dd) : 0.f);
    int p = atomicAdd(&cursor[d], 1);
    int idx = start[d] + p;
    csr_src[idx] = s;
    csr_norm[idx] = nm;
}

// ---------------- feature row-normalize: x = feat / rowsum(feat) ----------------

__global__ void k_norm_feat(const float* __restrict__ feat, float* __restrict__ x, int N) {
    int node = (blockIdx.x * blockDim.x + threadIdx.x) >> 6;
    int lane = threadIdx.x & 63;
    if (node >= N) return;
    const float* f = feat + (size_t)node * D;
    float a = f[lane], b = f[lane + 64];
    float s = a + b;
    #pragma unroll
    for (int off = 32; off > 0; off >>= 1) s += __shfl_down(s, off);
    s = __shfl(s, 0);
    float inv = 1.0f / s;
    x[(size_t)node * D + lane] = a * inv;
    x[(size_t)node * D + 64 + lane] = b * inv;
}

// ---------------- GEMM: Y[N,128] = X[N,128] @ W[128,128] ----------------
// block: 256 threads, 32 rows; W fully in LDS (64KB) + X tile (16KB).
// SAFE IN-PLACE (Y may alias X): each block stages its own 32 rows in LDS
// behind a barrier before writing, and blocks touch disjoint rows.

#define GEMM_ROWS 32

__global__ __launch_bounds__(256, 2) void k_gemm(const float* __restrict__ X,
                                                 const float* __restrict__ W,
                                                 float* __restrict__ Y, int nrows) {
    __shared__ float Wl[D * D];
    __shared__ float Xl[GEMM_ROWS * D];
    int t = threadIdx.x;
    const float4* W4 = (const float4*)W;
    float4* Wl4 = (float4*)Wl;
    #pragma unroll
    for (int i = 0; i < 16; i++) Wl4[t + i * 256] = W4[t + i * 256];

    int rowbase = blockIdx.x * GEMM_ROWS;
    const float4* X4 = (const float4*)(X + (size_t)rowbase * D);
    float4* Xl4 = (float4*)Xl;
    #pragma unroll
    for (int i = 0; i < 4; i++) {
        int idx = t + i * 256;          // float4 index in tile (32 float4 per row)
        int r = idx >> 5;
        float4 v;
        if (rowbase + r < nrows) v = X4[idx];
        else { v.x = v.y = v.z = v.w = 0.f; }
        Xl4[idx] = v;
    }
    __syncthreads();

    int cgrp = t & 31;  int c0 = cgrp * 4;
    int rgrp = t >> 5;  int r0 = rgrp * 4;
    float acc[4][4] = {};
    for (int k = 0; k < D; k += 4) {
        float xv[4][4], wv[4][4];
        #pragma unroll
        for (int r = 0; r < 4; r++) {
            float4 v = *(const float4*)&Xl[(r0 + r) * D + k];
            xv[r][0] = v.x; xv[r][1] = v.y; xv[r][2] = v.z; xv[r][3] = v.w;
        }
        #pragma unroll
        for (int kk = 0; kk < 4; kk++) {
            float4 v = *(const float4*)&Wl[(k + kk) * D + c0];
            wv[kk][0] = v.x; wv[kk][1] = v.y; wv[kk][2] = v.z; wv[kk][3] = v.w;
        }
        #pragma unroll
        for (int r = 0; r < 4; r++)
            #pragma unroll
            for (int c = 0; c < 4; c++)
                #pragma unroll
                for (int kk = 0; kk < 4; kk++)
                    acc[r][c] += xv[r][kk] * wv[kk][c];
    }

    #pragma unroll
    for (int r = 0; r < 4; r++) {
        int row = rowbase + r0 + r;
        if (row < nrows) {
            float4 v;
            v.x = acc[r][0]; v.y = acc[r][1]; v.z = acc[r][2]; v.w = acc[r][3];
            *(float4*)&Y[(size_t)row * D + c0] = v;
        }
    }
}

// ---------------- aggregation: out[n] = act( sum_e norm_e * Y[src_e] + b ) ----------------

__global__ void k_agg(const float* __restrict__ Y, const int* __restrict__ csr_src,
                      const float* __restrict__ csr_norm, const int* __restrict__ start,
                      const float* __restrict__ bias, float* __restrict__ Out,
                      int leaky, int N) {
    int node = (blockIdx.x * blockDim.x + threadIdx.x) >> 6;
    int lane = threadIdx.x & 63;
    if (node >= N) return;
    int s0 = start[node], s1 = start[node + 1];
    float acc0 = 0.f, acc1 = 0.f;
    for (int i = s0; i < s1; i++) {
        int s = csr_src[i];
        float nm = csr_norm[i];
        const float* yr = Y + (size_t)s * D;
        acc0 += nm * yr[lane];
        acc1 += nm * yr[lane + 64];
    }
    float v0 = acc0 + bias[lane];
    float v1 = acc1 + bias[lane + 64];
    if (leaky) {
        v0 = v0 > 0.f ? v0 : LEAKY * v0;
        v1 = v1 > 0.f ? v1 : LEAKY * v1;
    }
    Out[(size_t)node * D + lane] = v0;
    Out[(size_t)node * D + 64 + lane] = v1;
}

// ---------------- launch ----------------

extern "C" void kernel_launch(void* const* d_in, const int* in_sizes, int n_in,
                              void* d_out, int out_size, void* d_ws, size_t ws_size,
                              hipStream_t stream) {
    const float* feat = (const float*)d_in[0];
    const int*   eidx = (const int*)d_in[1];
    const float* ew   = (const float*)d_in[2];
    const float* W1   = (const float*)d_in[3];
    const float* b1   = (const float*)d_in[4];
    const float* W2   = (const float*)d_in[5];
    const float* b2   = (const float*)d_in[6];
    const float* W3   = (const float*)d_in[7];
    const float* b3   = (const float*)d_in[8];

    const int N = in_sizes[0] / D;   // 50000
    const int E = in_sizes[2];       // 600000
    const int* src = eidx;
    const int* dst = eidx + E;

    // workspace layout (4B units); total ~31.5 MB
    size_t off = 0;
    char* base = (char*)d_ws;
    auto alloc4 = [&](size_t elems) -> void* {
        void* p = base + off * 4;
        off += (elems + 3) & ~(size_t)3;
        return p;
    };
    float* rowsum   = (float*)alloc4(N);
    float* deg      = (float*)alloc4(N);
    int*   cnt      = (int*)  alloc4(N);
    int*   start    = (int*)  alloc4(N + 1);
    int*   cursor   = (int*)  alloc4(N);
    int*   partial  = (int*)  alloc4(64);
    char*  zero_end = base + off * 4;
    int*   csr_src  = (int*)  alloc4(E);
    float* csr_norm = (float*)alloc4(E);
    float* xbuf     = (float*)alloc4((size_t)N * D);
    float* outp     = (float*)d_out;

    // zero meta region (rowsum..partial)
    hipMemsetAsync(rowsum, 0, (size_t)(zero_end - (char*)rowsum), stream);

    int eblocks = (E + 255) / 256;
    int nchunks = (N + SCAN_CHUNK - 1) / SCAN_CHUNK;
    int wblocks = (N + 3) / 4;              // wave-per-node kernels
    int gblocks = (N + GEMM_ROWS - 1) / GEMM_ROWS;

    k_edge_rowsum<<<eblocks, 256, 0, stream>>>(src, ew, rowsum, E);
    k_edge_deg<<<eblocks, 256, 0, stream>>>(src, dst, ew, rowsum, deg, cnt, E);

    k_chunk_sum<<<nchunks, 256, 0, stream>>>(cnt, partial, N);
    k_scan_partial<<<1, 64, 0, stream>>>(partial, nchunks);
    k_chunk_scan<<<nchunks, 256, 0, stream>>>(cnt, partial, start, N, E);
    k_scatter_norm<<<eblocks, 256, 0, stream>>>(src, dst, ew, rowsum, deg, start,
                                                cursor, csr_src, csr_norm, E);

    k_norm_feat<<<wblocks, 256, 0, stream>>>(feat, xbuf, N);

    // layer 1: gemm in-place x->x, agg x->out (leaky)
    k_gemm<<<gblocks, 256, 0, stream>>>(xbuf, W1, xbuf, N);
    k_agg<<<wblocks, 256, 0, stream>>>(xbuf, csr_src, csr_norm, start, b1, outp, 1, N);
    // layer 2: gemm in-place out->out, agg out->x (leaky)
    k_gemm<<<gblocks, 256, 0, stream>>>(outp, W2, outp, N);
    k_agg<<<wblocks, 256, 0, stream>>>(outp, csr_src, csr_norm, start, b2, xbuf, 1, N);
    // layer 3: gemm in-place x->x, agg x->out (no activation)
    k_gemm<<<gblocks, 256, 0, stream>>>(xbuf, W3, xbuf, N);
    k_agg<<<wblocks, 256, 0, stream>>>(xbuf, csr_src, csr_norm, start, b3, outp, 0, N);
}

// Round 3
// 475.327 us; speedup vs baseline: 1.1345x; 1.1345x over previous
//
#include <hip/hip_runtime.h>

#define D 128
#define LEAKY 0.01f
#define SCAN_CHUNK 2048   // 256 threads x 8 elements

// ---------------- edge preprocessing ----------------

// pass 1: rowsum over src (A's row sums) + in-degree count over dst
__global__ void k_edge_rowsum_cnt(const int* __restrict__ src, const int* __restrict__ dst,
                                  const float* __restrict__ w, float* __restrict__ rowsum,
                                  int* __restrict__ cnt, int E) {
    int e = blockIdx.x * 256 + threadIdx.x;
    if (e >= E) return;
    atomicAdd(&rowsum[src[e]], w[e]);
    atomicAdd(&cnt[dst[e]], 1);
}

// pass 2: deg[d] = sum of w_hat over dst
__global__ void k_edge_deg(const int* __restrict__ src, const int* __restrict__ dst,
                           const float* __restrict__ w, const float* __restrict__ rowsum,
                           float* __restrict__ deg, int E) {
    int e = blockIdx.x * 256 + threadIdx.x;
    if (e >= E) return;
    int s = src[e], d = dst[e];
    float rs = rowsum[s], rd = rowsum[d];
    float wh = w[e] * (rs > 0.f ? 1.f / rs : 0.f) * (rd > 0.f ? 1.f / rd : 0.f);
    atomicAdd(&deg[d], wh);
}

// ---------------- prefix scan (3-phase) over cnt[N] -> start[N+1] ----------------

__global__ void k_chunk_sum(const int* __restrict__ cnt, int* __restrict__ partial, int n) {
    __shared__ int sdata[256];
    int b = blockIdx.x;
    int base = b * SCAN_CHUNK;
    int s = 0;
    for (int i = threadIdx.x; i < SCAN_CHUNK; i += 256) {
        int idx = base + i;
        s += (idx < n) ? cnt[idx] : 0;
    }
    sdata[threadIdx.x] = s;
    __syncthreads();
    for (int off = 128; off > 0; off >>= 1) {
        if (threadIdx.x < off) sdata[threadIdx.x] += sdata[threadIdx.x + off];
        __syncthreads();
    }
    if (threadIdx.x == 0) partial[b] = sdata[0];
}

__global__ void k_scan_partial(int* __restrict__ partial, int nchunks) {
    if (blockIdx.x == 0 && threadIdx.x == 0) {
        int run = 0;
        for (int i = 0; i < nchunks; i++) { int v = partial[i]; partial[i] = run; run += v; }
    }
}

__global__ void k_chunk_scan(const int* __restrict__ cnt, const int* __restrict__ partial,
                             int* __restrict__ start, int n, int total) {
    __shared__ int sdata[256];
    int b = blockIdx.x;
    int base = b * SCAN_CHUNK;
    int t = threadIdx.x;
    int loc[8];
    int s = 0;
    int tb = base + t * 8;
    #pragma unroll
    for (int j = 0; j < 8; j++) {
        int idx = tb + j;
        int v = (idx < n) ? cnt[idx] : 0;
        loc[j] = s;
        s += v;
    }
    sdata[t] = s;
    __syncthreads();
    for (int off = 1; off < 256; off <<= 1) {
        int v = (t >= off) ? sdata[t - off] : 0;
        __syncthreads();
        sdata[t] += v;
        __syncthreads();
    }
    int texcl = (t == 0) ? 0 : sdata[t - 1];
    int offb = partial[b];
    #pragma unroll
    for (int j = 0; j < 8; j++) {
        int idx = tb + j;
        if (idx < n) start[idx] = offb + texcl + loc[j];
    }
    if (b == gridDim.x - 1 && t == 255) start[n] = total;
}

// fused: recompute w_hat, apply symmetric norm, scatter into dst-CSR
__global__ void k_scatter_norm(const int* __restrict__ src, const int* __restrict__ dst,
                               const float* __restrict__ w, const float* __restrict__ rowsum,
                               const float* __restrict__ deg, const int* __restrict__ start,
                               int* __restrict__ cursor, int* __restrict__ csr_src,
                               float* __restrict__ csr_norm, int E) {
    int e = blockIdx.x * 256 + threadIdx.x;
    if (e >= E) return;
    int s = src[e], d = dst[e];
    float rs = rowsum[s], rd = rowsum[d];
    float wh = w[e] * (rs > 0.f ? 1.f / rs : 0.f) * (rd > 0.f ? 1.f / rd : 0.f);
    float ds = deg[s], dd = deg[d];
    float nm = wh * (ds > 0.f ? rsqrtf(ds) : 0.f) * (dd > 0.f ? rsqrtf(dd) : 0.f);
    int p = atomicAdd(&cursor[d], 1);
    int idx = start[d] + p;
    csr_src[idx] = s;
    csr_norm[idx] = nm;
}

// ---------------- feature row-normalize: x = feat / rowsum(feat) ----------------

__global__ void k_norm_feat(const float* __restrict__ feat, float* __restrict__ x, int N) {
    int node = (blockIdx.x * blockDim.x + threadIdx.x) >> 6;
    int lane = threadIdx.x & 63;
    if (node >= N) return;
    const float* f = feat + (size_t)node * D;
    float a = f[lane], b = f[lane + 64];
    float s = a + b;
    #pragma unroll
    for (int off = 32; off > 0; off >>= 1) s += __shfl_down(s, off);
    s = __shfl(s, 0);
    float inv = 1.0f / s;
    x[(size_t)node * D + lane] = a * inv;
    x[(size_t)node * D + 64 + lane] = b * inv;
}

// ---------------- GEMM: Y[N,128] = X[N,128] @ W[128,128] ----------------
// block: 256 threads, 32 rows; W fully in LDS (64KB) + X tile (16KB).
// SAFE IN-PLACE (Y may alias X): each block stages its own 32 rows in LDS
// behind a barrier before writing, and blocks touch disjoint rows.

#define GEMM_ROWS 32

__global__ __launch_bounds__(256, 2) void k_gemm(const float* __restrict__ X,
                                                 const float* __restrict__ W,
                                                 float* __restrict__ Y, int nrows) {
    __shared__ float Wl[D * D];
    __shared__ float Xl[GEMM_ROWS * D];
    int t = threadIdx.x;
    const float4* W4 = (const float4*)W;
    float4* Wl4 = (float4*)Wl;
    #pragma unroll
    for (int i = 0; i < 16; i++) Wl4[t + i * 256] = W4[t + i * 256];

    int rowbase = blockIdx.x * GEMM_ROWS;
    const float4* X4 = (const float4*)(X + (size_t)rowbase * D);
    float4* Xl4 = (float4*)Xl;
    #pragma unroll
    for (int i = 0; i < 4; i++) {
        int idx = t + i * 256;          // float4 index in tile (32 float4 per row)
        int r = idx >> 5;
        float4 v;
        if (rowbase + r < nrows) v = X4[idx];
        else { v.x = v.y = v.z = v.w = 0.f; }
        Xl4[idx] = v;
    }
    __syncthreads();

    int cgrp = t & 31;  int c0 = cgrp * 4;
    int rgrp = t >> 5;  int r0 = rgrp * 4;
    float acc[4][4] = {};
    for (int k = 0; k < D; k += 4) {
        float xv[4][4], wv[4][4];
        #pragma unroll
        for (int r = 0; r < 4; r++) {
            float4 v = *(const float4*)&Xl[(r0 + r) * D + k];
            xv[r][0] = v.x; xv[r][1] = v.y; xv[r][2] = v.z; xv[r][3] = v.w;
        }
        #pragma unroll
        for (int kk = 0; kk < 4; kk++) {
            float4 v = *(const float4*)&Wl[(k + kk) * D + c0];
            wv[kk][0] = v.x; wv[kk][1] = v.y; wv[kk][2] = v.z; wv[kk][3] = v.w;
        }
        #pragma unroll
        for (int r = 0; r < 4; r++)
            #pragma unroll
            for (int c = 0; c < 4; c++)
                #pragma unroll
                for (int kk = 0; kk < 4; kk++)
                    acc[r][c] += xv[r][kk] * wv[kk][c];
    }

    #pragma unroll
    for (int r = 0; r < 4; r++) {
        int row = rowbase + r0 + r;
        if (row < nrows) {
            float4 v;
            v.x = acc[r][0]; v.y = acc[r][1]; v.z = acc[r][2]; v.w = acc[r][3];
            *(float4*)&Y[(size_t)row * D + c0] = v;
        }
    }
}

// ---------------- aggregation ----------------
// 2 nodes per wave: each 32-lane half owns a node; lane reads float4 (row =
// 32 lanes x 16B). Edge (src,norm) prefetched lane-parallel (32 at a time),
// broadcast via __shfl(width=32); gather unrolled 4x for MLP.

__global__ void k_agg(const float* __restrict__ Y, const int* __restrict__ csr_src,
                      const float* __restrict__ csr_norm, const int* __restrict__ start,
                      const float* __restrict__ bias, float* __restrict__ Out,
                      int leaky, int N) {
    int wid = (blockIdx.x * blockDim.x + threadIdx.x) >> 6;
    int lane = threadIdx.x & 63;
    int half = lane >> 5;
    int l = lane & 31;
    int node = wid * 2 + half;
    bool valid = node < N;
    int s0 = valid ? start[node] : 0;
    int s1 = valid ? start[node + 1] : 0;
    int cnt = s1 - s0;

    float4 acc = {0.f, 0.f, 0.f, 0.f};
    const float4* Y4 = (const float4*)Y;

    for (int base = 0; base < cnt; base += 32) {
        int rem = cnt - base; if (rem > 32) rem = 32;
        int eidx = s0 + base + l;
        int  sj = (l < rem) ? csr_src[eidx] : 0;
        float nj = (l < rem) ? csr_norm[eidx] : 0.f;
        int j = 0;
        for (; j + 4 <= rem; j += 4) {
            int   i0 = __shfl(sj, j + 0, 32), i1 = __shfl(sj, j + 1, 32);
            int   i2 = __shfl(sj, j + 2, 32), i3 = __shfl(sj, j + 3, 32);
            float n0 = __shfl(nj, j + 0, 32), n1 = __shfl(nj, j + 1, 32);
            float n2 = __shfl(nj, j + 2, 32), n3 = __shfl(nj, j + 3, 32);
            float4 v0 = Y4[(size_t)i0 * 32 + l];
            float4 v1 = Y4[(size_t)i1 * 32 + l];
            float4 v2 = Y4[(size_t)i2 * 32 + l];
            float4 v3 = Y4[(size_t)i3 * 32 + l];
            acc.x += n0 * v0.x; acc.y += n0 * v0.y; acc.z += n0 * v0.z; acc.w += n0 * v0.w;
            acc.x += n1 * v1.x; acc.y += n1 * v1.y; acc.z += n1 * v1.z; acc.w += n1 * v1.w;
            acc.x += n2 * v2.x; acc.y += n2 * v2.y; acc.z += n2 * v2.z; acc.w += n2 * v2.w;
            acc.x += n3 * v3.x; acc.y += n3 * v3.y; acc.z += n3 * v3.z; acc.w += n3 * v3.w;
        }
        for (; j < rem; j++) {
            int   i0 = __shfl(sj, j, 32);
            float n0 = __shfl(nj, j, 32);
            float4 v0 = Y4[(size_t)i0 * 32 + l];
            acc.x += n0 * v0.x; acc.y += n0 * v0.y; acc.z += n0 * v0.z; acc.w += n0 * v0.w;
        }
    }

    if (!valid) return;
    float4 b4 = ((const float4*)bias)[l];
    float4 v;
    v.x = acc.x + b4.x; v.y = acc.y + b4.y; v.z = acc.z + b4.z; v.w = acc.w + b4.w;
    if (leaky) {
        v.x = v.x > 0.f ? v.x : LEAKY * v.x;
        v.y = v.y > 0.f ? v.y : LEAKY * v.y;
        v.z = v.z > 0.f ? v.z : LEAKY * v.z;
        v.w = v.w > 0.f ? v.w : LEAKY * v.w;
    }
    ((float4*)Out)[(size_t)node * 32 + l] = v;
}

// ---------------- launch ----------------

extern "C" void kernel_launch(void* const* d_in, const int* in_sizes, int n_in,
                              void* d_out, int out_size, void* d_ws, size_t ws_size,
                              hipStream_t stream) {
    const float* feat = (const float*)d_in[0];
    const int*   eidx = (const int*)d_in[1];
    const float* ew   = (const float*)d_in[2];
    const float* W1   = (const float*)d_in[3];
    const float* b1   = (const float*)d_in[4];
    const float* W2   = (const float*)d_in[5];
    const float* b2   = (const float*)d_in[6];
    const float* W3   = (const float*)d_in[7];
    const float* b3   = (const float*)d_in[8];

    const int N = in_sizes[0] / D;   // 50000
    const int E = in_sizes[2];       // 600000
    const int* src = eidx;
    const int* dst = eidx + E;

    // workspace layout (4B units); total ~31.5 MB
    size_t off = 0;
    char* base = (char*)d_ws;
    auto alloc4 = [&](size_t elems) -> void* {
        void* p = base + off * 4;
        off += (elems + 3) & ~(size_t)3;
        return p;
    };
    float* rowsum   = (float*)alloc4(N);
    float* deg      = (float*)alloc4(N);
    int*   cnt      = (int*)  alloc4(N);
    int*   start    = (int*)  alloc4(N + 1);
    int*   cursor   = (int*)  alloc4(N);
    int*   partial  = (int*)  alloc4(64);
    char*  zero_end = base + off * 4;
    int*   csr_src  = (int*)  alloc4(E);
    float* csr_norm = (float*)alloc4(E);
    float* xbuf     = (float*)alloc4((size_t)N * D);
    float* outp     = (float*)d_out;

    // zero meta region (rowsum..partial)
    hipMemsetAsync(rowsum, 0, (size_t)(zero_end - (char*)rowsum), stream);

    int eblocks = (E + 255) / 256;
    int nchunks = (N + SCAN_CHUNK - 1) / SCAN_CHUNK;
    int wblocks = (N + 3) / 4;                    // k_norm_feat: wave per node
    int ablocks = ((N + 1) / 2 * 64 + 255) / 256; // k_agg: 2 nodes per wave
    int gblocks = (N + GEMM_ROWS - 1) / GEMM_ROWS;

    k_edge_rowsum_cnt<<<eblocks, 256, 0, stream>>>(src, dst, ew, rowsum, cnt, E);
    k_edge_deg<<<eblocks, 256, 0, stream>>>(src, dst, ew, rowsum, deg, E);

    k_chunk_sum<<<nchunks, 256, 0, stream>>>(cnt, partial, N);
    k_scan_partial<<<1, 64, 0, stream>>>(partial, nchunks);
    k_chunk_scan<<<nchunks, 256, 0, stream>>>(cnt, partial, start, N, E);
    k_scatter_norm<<<eblocks, 256, 0, stream>>>(src, dst, ew, rowsum, deg, start,
                                                cursor, csr_src, csr_norm, E);

    k_norm_feat<<<wblocks, 256, 0, stream>>>(feat, xbuf, N);

    // layer 1: gemm in-place x->x, agg x->out (leaky)
    k_gemm<<<gblocks, 256, 0, stream>>>(xbuf, W1, xbuf, N);
    k_agg<<<ablocks, 256, 0, stream>>>(xbuf, csr_src, csr_norm, start, b1, outp, 1, N);
    // layer 2: gemm in-place out->out, agg out->x (leaky)
    k_gemm<<<gblocks, 256, 0, stream>>>(outp, W2, outp, N);
    k_agg<<<ablocks, 256, 0, stream>>>(outp, csr_src, csr_norm, start, b2, xbuf, 1, N);
    // layer 3: gemm in-place x->x, agg x->out (no activation)
    k_gemm<<<gblocks, 256, 0, stream>>>(xbuf, W3, xbuf, N);
    k_agg<<<ablocks, 256, 0, stream>>>(xbuf, csr_src, csr_norm, start, b3, outp, 0, N);
}

// Round 4
// 437.920 us; speedup vs baseline: 1.2314x; 1.0854x over previous
//
#include <hip/hip_runtime.h>

#define D 128
#define LEAKY 0.01f
#define SCAN_CHUNK 2048   // 256 threads x 8 elements

// ---------------- pass 1: rowsum over src (atomic) + dst histogram w/ rank ----------------
// rank[e] = this edge's slot among edges sharing dst  -> scatter needs no atomics later.

__global__ void k_pass1(const int* __restrict__ src, const int* __restrict__ dst,
                        const float* __restrict__ w, float* __restrict__ rowsum,
                        int* __restrict__ cnt, int* __restrict__ rank, int E) {
    int e = blockIdx.x * 256 + threadIdx.x;
    if (e >= E) return;
    atomicAdd(&rowsum[src[e]], w[e]);
    rank[e] = atomicAdd(&cnt[dst[e]], 1);
}

// ---------------- prefix scan (3-phase) over cnt[N] -> start[N+1] ----------------

__global__ void k_chunk_sum(const int* __restrict__ cnt, int* __restrict__ partial, int n) {
    __shared__ int sdata[256];
    int b = blockIdx.x;
    int base = b * SCAN_CHUNK;
    int s = 0;
    for (int i = threadIdx.x; i < SCAN_CHUNK; i += 256) {
        int idx = base + i;
        s += (idx < n) ? cnt[idx] : 0;
    }
    sdata[threadIdx.x] = s;
    __syncthreads();
    for (int off = 128; off > 0; off >>= 1) {
        if (threadIdx.x < off) sdata[threadIdx.x] += sdata[threadIdx.x + off];
        __syncthreads();
    }
    if (threadIdx.x == 0) partial[b] = sdata[0];
}

__global__ void k_scan_partial(int* __restrict__ partial, int nchunks) {
    if (blockIdx.x == 0 && threadIdx.x == 0) {
        int run = 0;
        for (int i = 0; i < nchunks; i++) { int v = partial[i]; partial[i] = run; run += v; }
    }
}

__global__ void k_chunk_scan(const int* __restrict__ cnt, const int* __restrict__ partial,
                             int* __restrict__ start, int n, int total) {
    __shared__ int sdata[256];
    int b = blockIdx.x;
    int base = b * SCAN_CHUNK;
    int t = threadIdx.x;
    int loc[8];
    int s = 0;
    int tb = base + t * 8;
    #pragma unroll
    for (int j = 0; j < 8; j++) {
        int idx = tb + j;
        int v = (idx < n) ? cnt[idx] : 0;
        loc[j] = s;
        s += v;
    }
    sdata[t] = s;
    __syncthreads();
    for (int off = 1; off < 256; off <<= 1) {
        int v = (t >= off) ? sdata[t - off] : 0;
        __syncthreads();
        sdata[t] += v;
        __syncthreads();
    }
    int texcl = (t == 0) ? 0 : sdata[t - 1];
    int offb = partial[b];
    #pragma unroll
    for (int j = 0; j < 8; j++) {
        int idx = tb + j;
        if (idx < n) start[idx] = offb + texcl + loc[j];
    }
    if (b == gridDim.x - 1 && t == 255) start[n] = total;
}

// ---------------- scatter (NO atomics): compute w_hat, place at start[d]+rank[e] ----------------

__global__ void k_scatter2(const int* __restrict__ src, const int* __restrict__ dst,
                           const float* __restrict__ w, const float* __restrict__ rowsum,
                           const int* __restrict__ start, const int* __restrict__ rank,
                           int* __restrict__ csr_src, float* __restrict__ csr_wh, int E) {
    int e = blockIdx.x * 256 + threadIdx.x;
    if (e >= E) return;
    int s = src[e], d = dst[e];
    float rs = rowsum[s], rd = rowsum[d];
    float wh = w[e] * (rs > 0.f ? 1.f / rs : 0.f) * (rd > 0.f ? 1.f / rd : 0.f);
    int idx = start[d] + rank[e];
    csr_src[idx] = s;
    csr_wh[idx] = wh;
}

// ---------------- deg via contiguous segment gather (no atomics) -> dinv ----------------

__global__ void k_deg_dinv(const float* __restrict__ csr_wh, const int* __restrict__ start,
                           float* __restrict__ dinv, int N) {
    int n = blockIdx.x * 256 + threadIdx.x;
    if (n >= N) return;
    int s0 = start[n], s1 = start[n + 1];
    float s = 0.f;
    for (int i = s0; i < s1; i++) s += csr_wh[i];
    dinv[n] = s > 0.f ? rsqrtf(s) : 0.f;
}

// ---------------- finalize norm in place: csr[i] *= dinv[src]*dinv[dstnode] ----------------
// 16-lane groups, one node per group (avg segment = 12)

__global__ void k_csr_norm(float* __restrict__ csr_wh, const int* __restrict__ csr_src,
                           const int* __restrict__ start, const float* __restrict__ dinv, int N) {
    int g = (blockIdx.x * blockDim.x + threadIdx.x) >> 4;
    int l = threadIdx.x & 15;
    if (g >= N) return;
    int s0 = start[g], s1 = start[g + 1];
    float dd = dinv[g];
    for (int i = s0 + l; i < s1; i += 16)
        csr_wh[i] = csr_wh[i] * dinv[csr_src[i]] * dd;
}

// ---------------- GEMM: Y[N,128] = X[N,128] @ W[128,128] ----------------
// block: 256 threads, 32 rows; W fully in LDS (64KB) + X tile (16KB).
// do_norm: row-normalize the staged X tile first (fused feat-normalize, layer 1).
// SAFE IN-PLACE (Y may alias X): each block stages its own 32 rows in LDS
// behind a barrier before writing, and blocks touch disjoint rows.

#define GEMM_ROWS 32

__global__ __launch_bounds__(256, 2) void k_gemm(const float* __restrict__ X,
                                                 const float* __restrict__ W,
                                                 float* __restrict__ Y, int nrows,
                                                 int do_norm) {
    __shared__ float Wl[D * D];
    __shared__ float Xl[GEMM_ROWS * D];
    int t = threadIdx.x;
    const float4* W4 = (const float4*)W;
    float4* Wl4 = (float4*)Wl;
    #pragma unroll
    for (int i = 0; i < 16; i++) Wl4[t + i * 256] = W4[t + i * 256];

    int rowbase = blockIdx.x * GEMM_ROWS;
    const float4* X4 = (const float4*)(X + (size_t)rowbase * D);
    float4* Xl4 = (float4*)Xl;
    #pragma unroll
    for (int i = 0; i < 4; i++) {
        int idx = t + i * 256;          // float4 index in tile (32 float4 per row)
        int r = idx >> 5;
        float4 v;
        if (rowbase + r < nrows) v = X4[idx];
        else { v.x = v.y = v.z = v.w = 0.f; }
        Xl4[idx] = v;
    }
    __syncthreads();

    if (do_norm) {
        // 8 threads per row; each owns 4 float4 (16 floats) of its row
        int r = t >> 3, j = t & 7;
        float4 a0 = Xl4[r * 32 + j];
        float4 a1 = Xl4[r * 32 + j + 8];
        float4 a2 = Xl4[r * 32 + j + 16];
        float4 a3 = Xl4[r * 32 + j + 24];
        float s = a0.x + a0.y + a0.z + a0.w + a1.x + a1.y + a1.z + a1.w
                + a2.x + a2.y + a2.z + a2.w + a3.x + a3.y + a3.z + a3.w;
        s += __shfl_down(s, 4, 8);
        s += __shfl_down(s, 2, 8);
        s += __shfl_down(s, 1, 8);
        float tot = __shfl(s, 0, 8);
        float inv = tot > 0.f ? 1.f / tot : 0.f;
        a0.x *= inv; a0.y *= inv; a0.z *= inv; a0.w *= inv;
        a1.x *= inv; a1.y *= inv; a1.z *= inv; a1.w *= inv;
        a2.x *= inv; a2.y *= inv; a2.z *= inv; a2.w *= inv;
        a3.x *= inv; a3.y *= inv; a3.z *= inv; a3.w *= inv;
        Xl4[r * 32 + j] = a0;
        Xl4[r * 32 + j + 8] = a1;
        Xl4[r * 32 + j + 16] = a2;
        Xl4[r * 32 + j + 24] = a3;
        __syncthreads();
    }

    int cgrp = t & 31;  int c0 = cgrp * 4;
    int rgrp = t >> 5;  int r0 = rgrp * 4;
    float acc[4][4] = {};
    for (int k = 0; k < D; k += 4) {
        float xv[4][4], wv[4][4];
        #pragma unroll
        for (int r = 0; r < 4; r++) {
            float4 v = *(const float4*)&Xl[(r0 + r) * D + k];
            xv[r][0] = v.x; xv[r][1] = v.y; xv[r][2] = v.z; xv[r][3] = v.w;
        }
        #pragma unroll
        for (int kk = 0; kk < 4; kk++) {
            float4 v = *(const float4*)&Wl[(k + kk) * D + c0];
            wv[kk][0] = v.x; wv[kk][1] = v.y; wv[kk][2] = v.z; wv[kk][3] = v.w;
        }
        #pragma unroll
        for (int r = 0; r < 4; r++)
            #pragma unroll
            for (int c = 0; c < 4; c++)
                #pragma unroll
                for (int kk = 0; kk < 4; kk++)
                    acc[r][c] += xv[r][kk] * wv[kk][c];
    }

    #pragma unroll
    for (int r = 0; r < 4; r++) {
        int row = rowbase + r0 + r;
        if (row < nrows) {
            float4 v;
            v.x = acc[r][0]; v.y = acc[r][1]; v.z = acc[r][2]; v.w = acc[r][3];
            *(float4*)&Y[(size_t)row * D + c0] = v;
        }
    }
}

// ---------------- aggregation ----------------
// 2 nodes per wave: each 32-lane half owns a node; lane reads float4 (row =
// 32 lanes x 16B). Edge (src,norm) prefetched lane-parallel (32 at a time),
// broadcast via __shfl(width=32); gather unrolled 4x for MLP.

__global__ void k_agg(const float* __restrict__ Y, const int* __restrict__ csr_src,
                      const float* __restrict__ csr_norm, const int* __restrict__ start,
                      const float* __restrict__ bias, float* __restrict__ Out,
                      int leaky, int N) {
    int wid = (blockIdx.x * blockDim.x + threadIdx.x) >> 6;
    int lane = threadIdx.x & 63;
    int half = lane >> 5;
    int l = lane & 31;
    int node = wid * 2 + half;
    bool valid = node < N;
    int s0 = valid ? start[node] : 0;
    int s1 = valid ? start[node + 1] : 0;
    int cnt = s1 - s0;

    float4 acc = {0.f, 0.f, 0.f, 0.f};
    const float4* Y4 = (const float4*)Y;

    for (int base = 0; base < cnt; base += 32) {
        int rem = cnt - base; if (rem > 32) rem = 32;
        int eidx = s0 + base + l;
        int  sj = (l < rem) ? csr_src[eidx] : 0;
        float nj = (l < rem) ? csr_norm[eidx] : 0.f;
        int j = 0;
        for (; j + 4 <= rem; j += 4) {
            int   i0 = __shfl(sj, j + 0, 32), i1 = __shfl(sj, j + 1, 32);
            int   i2 = __shfl(sj, j + 2, 32), i3 = __shfl(sj, j + 3, 32);
            float n0 = __shfl(nj, j + 0, 32), n1 = __shfl(nj, j + 1, 32);
            float n2 = __shfl(nj, j + 2, 32), n3 = __shfl(nj, j + 3, 32);
            float4 v0 = Y4[(size_t)i0 * 32 + l];
            float4 v1 = Y4[(size_t)i1 * 32 + l];
            float4 v2 = Y4[(size_t)i2 * 32 + l];
            float4 v3 = Y4[(size_t)i3 * 32 + l];
            acc.x += n0 * v0.x; acc.y += n0 * v0.y; acc.z += n0 * v0.z; acc.w += n0 * v0.w;
            acc.x += n1 * v1.x; acc.y += n1 * v1.y; acc.z += n1 * v1.z; acc.w += n1 * v1.w;
            acc.x += n2 * v2.x; acc.y += n2 * v2.y; acc.z += n2 * v2.z; acc.w += n2 * v2.w;
            acc.x += n3 * v3.x; acc.y += n3 * v3.y; acc.z += n3 * v3.z; acc.w += n3 * v3.w;
        }
        for (; j < rem; j++) {
            int   i0 = __shfl(sj, j, 32);
            float n0 = __shfl(nj, j, 32);
            float4 v0 = Y4[(size_t)i0 * 32 + l];
            acc.x += n0 * v0.x; acc.y += n0 * v0.y; acc.z += n0 * v0.z; acc.w += n0 * v0.w;
        }
    }

    if (!valid) return;
    float4 b4 = ((const float4*)bias)[l];
    float4 v;
    v.x = acc.x + b4.x; v.y = acc.y + b4.y; v.z = acc.z + b4.z; v.w = acc.w + b4.w;
    if (leaky) {
        v.x = v.x > 0.f ? v.x : LEAKY * v.x;
        v.y = v.y > 0.f ? v.y : LEAKY * v.y;
        v.z = v.z > 0.f ? v.z : LEAKY * v.z;
        v.w = v.w > 0.f ? v.w : LEAKY * v.w;
    }
    ((float4*)Out)[(size_t)node * 32 + l] = v;
}

// ---------------- launch ----------------

extern "C" void kernel_launch(void* const* d_in, const int* in_sizes, int n_in,
                              void* d_out, int out_size, void* d_ws, size_t ws_size,
                              hipStream_t stream) {
    const float* feat = (const float*)d_in[0];
    const int*   eidx = (const int*)d_in[1];
    const float* ew   = (const float*)d_in[2];
    const float* W1   = (const float*)d_in[3];
    const float* b1   = (const float*)d_in[4];
    const float* W2   = (const float*)d_in[5];
    const float* b2   = (const float*)d_in[6];
    const float* W3   = (const float*)d_in[7];
    const float* b3   = (const float*)d_in[8];

    const int N = in_sizes[0] / D;   // 50000
    const int E = in_sizes[2];       // 600000
    const int* src = eidx;
    const int* dst = eidx + E;

    // workspace layout (4B units); total ~33.6 MB
    size_t off = 0;
    char* base = (char*)d_ws;
    auto alloc4 = [&](size_t elems) -> void* {
        void* p = base + off * 4;
        off += (elems + 3) & ~(size_t)3;
        return p;
    };
    float* rowsum   = (float*)alloc4(N);      // zeroed
    int*   cnt      = (int*)  alloc4(N);      // zeroed (contiguous with rowsum)
    char*  zero_end = base + off * 4;
    int*   start    = (int*)  alloc4(N + 1);
    float* dinv     = (float*)alloc4(N);
    int*   partial  = (int*)  alloc4(64);
    int*   rank     = (int*)  alloc4(E);
    int*   csr_src  = (int*)  alloc4(E);
    float* csr_wh   = (float*)alloc4(E);      // becomes csr_norm in place
    float* xbuf     = (float*)alloc4((size_t)N * D);
    float* outp     = (float*)d_out;

    hipMemsetAsync(rowsum, 0, (size_t)(zero_end - (char*)rowsum), stream);

    int eblocks = (E + 255) / 256;
    int nchunks = (N + SCAN_CHUNK - 1) / SCAN_CHUNK;
    int nblocks = (N + 255) / 256;
    int cblocks = ((size_t)N * 16 + 255) / 256;   // k_csr_norm: 16 lanes/node
    int ablocks = ((N + 1) / 2 * 64 + 255) / 256; // k_agg: 2 nodes per wave
    int gblocks = (N + GEMM_ROWS - 1) / GEMM_ROWS;

    k_pass1<<<eblocks, 256, 0, stream>>>(src, dst, ew, rowsum, cnt, rank, E);

    k_chunk_sum<<<nchunks, 256, 0, stream>>>(cnt, partial, N);
    k_scan_partial<<<1, 64, 0, stream>>>(partial, nchunks);
    k_chunk_scan<<<nchunks, 256, 0, stream>>>(cnt, partial, start, N, E);

    k_scatter2<<<eblocks, 256, 0, stream>>>(src, dst, ew, rowsum, start, rank,
                                            csr_src, csr_wh, E);
    k_deg_dinv<<<nblocks, 256, 0, stream>>>(csr_wh, start, dinv, N);
    k_csr_norm<<<cblocks, 256, 0, stream>>>(csr_wh, csr_src, start, dinv, N);

    // layer 1: gemm feat->xbuf with fused row-normalize, agg xbuf->out (leaky)
    k_gemm<<<gblocks, 256, 0, stream>>>(feat, W1, xbuf, N, 1);
    k_agg<<<ablocks, 256, 0, stream>>>(xbuf, csr_src, csr_wh, start, b1, outp, 1, N);
    // layer 2: gemm in-place out->out, agg out->x (leaky)
    k_gemm<<<gblocks, 256, 0, stream>>>(outp, W2, outp, N, 0);
    k_agg<<<ablocks, 256, 0, stream>>>(outp, csr_src, csr_wh, start, b2, xbuf, 1, N);
    // layer 3: gemm in-place x->x, agg x->out (no activation)
    k_gemm<<<gblocks, 256, 0, stream>>>(xbuf, W3, xbuf, N, 0);
    k_agg<<<ablocks, 256, 0, stream>>>(xbuf, csr_src, csr_wh, start, b3, outp, 0, N);
}

// Round 5
// 435.566 us; speedup vs baseline: 1.2381x; 1.0054x over previous
//
#include <hip/hip_runtime.h>

#define D 128
#define LEAKY 0.01f
#define SCAN_CHUNK 2048   // 256 threads x 8 elements

// ---------------- pass 1: rowsum over src (atomic) + dst histogram w/ rank ----------------
// 4 edges per thread: 8 independent atomic chains in flight per thread.

__global__ void k_pass1(const int* __restrict__ src, const int* __restrict__ dst,
                        const float* __restrict__ w, float* __restrict__ rowsum,
                        int* __restrict__ cnt, int* __restrict__ rank, int E) {
    int base = blockIdx.x * 1024 + threadIdx.x;
    #pragma unroll
    for (int j = 0; j < 4; j++) {
        int e = base + j * 256;
        if (e < E) {
            atomicAdd(&rowsum[src[e]], w[e]);
            rank[e] = atomicAdd(&cnt[dst[e]], 1);
        }
    }
}

// ---------------- prefix scan (3-phase) over cnt[N] -> start[N+1] ----------------

__global__ void k_chunk_sum(const int* __restrict__ cnt, int* __restrict__ partial, int n) {
    __shared__ int sdata[256];
    int b = blockIdx.x;
    int base = b * SCAN_CHUNK;
    int s = 0;
    for (int i = threadIdx.x; i < SCAN_CHUNK; i += 256) {
        int idx = base + i;
        s += (idx < n) ? cnt[idx] : 0;
    }
    sdata[threadIdx.x] = s;
    __syncthreads();
    for (int off = 128; off > 0; off >>= 1) {
        if (threadIdx.x < off) sdata[threadIdx.x] += sdata[threadIdx.x + off];
        __syncthreads();
    }
    if (threadIdx.x == 0) partial[b] = sdata[0];
}

__global__ void k_scan_partial(int* __restrict__ partial, int nchunks) {
    if (blockIdx.x == 0 && threadIdx.x == 0) {
        int run = 0;
        for (int i = 0; i < nchunks; i++) { int v = partial[i]; partial[i] = run; run += v; }
    }
}

__global__ void k_chunk_scan(const int* __restrict__ cnt, const int* __restrict__ partial,
                             int* __restrict__ start, int n, int total) {
    __shared__ int sdata[256];
    int b = blockIdx.x;
    int base = b * SCAN_CHUNK;
    int t = threadIdx.x;
    int loc[8];
    int s = 0;
    int tb = base + t * 8;
    #pragma unroll
    for (int j = 0; j < 8; j++) {
        int idx = tb + j;
        int v = (idx < n) ? cnt[idx] : 0;
        loc[j] = s;
        s += v;
    }
    sdata[t] = s;
    __syncthreads();
    for (int off = 1; off < 256; off <<= 1) {
        int v = (t >= off) ? sdata[t - off] : 0;
        __syncthreads();
        sdata[t] += v;
        __syncthreads();
    }
    int texcl = (t == 0) ? 0 : sdata[t - 1];
    int offb = partial[b];
    #pragma unroll
    for (int j = 0; j < 8; j++) {
        int idx = tb + j;
        if (idx < n) start[idx] = offb + texcl + loc[j];
    }
    if (b == gridDim.x - 1 && t == 255) start[n] = total;
}

// ---------------- scatter (NO atomics): compute w_hat, place at start[d]+rank[e] ----------------
// CSR entry packed as int2 {src, bits(w_hat)} -> one 8B scattered store per edge.

__global__ void k_scatter2(const int* __restrict__ src, const int* __restrict__ dst,
                           const float* __restrict__ w, const float* __restrict__ rowsum,
                           const int* __restrict__ start, const int* __restrict__ rank,
                           int2* __restrict__ csr, int E) {
    int e = blockIdx.x * 256 + threadIdx.x;
    if (e >= E) return;
    int s = src[e], d = dst[e];
    float rs = rowsum[s], rd = rowsum[d];
    float wh = w[e] * (rs > 0.f ? 1.f / rs : 0.f) * (rd > 0.f ? 1.f / rd : 0.f);
    int idx = start[d] + rank[e];
    csr[idx] = make_int2(s, __float_as_int(wh));
}

// ---------------- deg via contiguous segment gather (no atomics) -> dinv ----------------

__global__ void k_deg_dinv(const int2* __restrict__ csr, const int* __restrict__ start,
                           float* __restrict__ dinv, int N) {
    int n = blockIdx.x * 256 + threadIdx.x;
    if (n >= N) return;
    int s0 = start[n], s1 = start[n + 1];
    float s = 0.f;
    for (int i = s0; i < s1; i++) s += __int_as_float(csr[i].y);
    dinv[n] = s > 0.f ? rsqrtf(s) : 0.f;
}

// ---------------- finalize norm in place: csr[i].wh *= dinv[src]*dinv[dstnode] ----------------
// 16-lane groups, one node per group (avg segment = 12)

__global__ void k_csr_norm(int2* __restrict__ csr, const int* __restrict__ start,
                           const float* __restrict__ dinv, int N) {
    int g = (blockIdx.x * blockDim.x + threadIdx.x) >> 4;
    int l = threadIdx.x & 15;
    if (g >= N) return;
    int s0 = start[g], s1 = start[g + 1];
    float dd = dinv[g];
    for (int i = s0 + l; i < s1; i += 16) {
        int2 p = csr[i];
        float nm = __int_as_float(p.y) * dinv[p.x] * dd;
        csr[i] = make_int2(p.x, __float_as_int(nm));
    }
}

// ---------------- GEMM: Y[N,128] = X[N,128] @ W[128,128] ----------------
// block: 256 threads; W staged ONCE into LDS (64KB), then 4 row-tiles of 32
// rows each (Xl 16KB, restaged per tile). 80KB LDS -> 2 blocks/CU.
// do_norm: row-normalize the staged X tile first (fused feat-normalize, layer 1).
// SAFE IN-PLACE (Y may alias X): each block writes only rows it staged, post-barrier.

#define GEMM_ROWS 32
#define GTILES 4

__global__ __launch_bounds__(256, 2) void k_gemm(const float* __restrict__ X,
                                                 const float* __restrict__ W,
                                                 float* __restrict__ Y, int nrows,
                                                 int do_norm) {
    __shared__ float Wl[D * D];
    __shared__ float Xl[GEMM_ROWS * D];
    int t = threadIdx.x;
    const float4* W4 = (const float4*)W;
    float4* Wl4 = (float4*)Wl;
    #pragma unroll
    for (int i = 0; i < 16; i++) Wl4[t + i * 256] = W4[t + i * 256];

    float4* Xl4 = (float4*)Xl;
    int cgrp = t & 31;  int c0 = cgrp * 4;
    int rgrp = t >> 5;  int r0 = rgrp * 4;

    for (int tile = 0; tile < GTILES; tile++) {
        int rowbase = (blockIdx.x * GTILES + tile) * GEMM_ROWS;
        if (rowbase >= nrows) break;                 // block-uniform
        __syncthreads();                              // Wl ready / prev tile done with Xl
        const float4* X4 = (const float4*)(X + (size_t)rowbase * D);
        #pragma unroll
        for (int i = 0; i < 4; i++) {
            int idx = t + i * 256;          // float4 index in tile (32 float4 per row)
            int r = idx >> 5;
            float4 v;
            if (rowbase + r < nrows) v = X4[idx];
            else { v.x = v.y = v.z = v.w = 0.f; }
            Xl4[idx] = v;
        }
        __syncthreads();

        if (do_norm) {
            // 8 threads per row; each owns 4 float4 (16 floats) of its row
            int r = t >> 3, j = t & 7;
            float4 a0 = Xl4[r * 32 + j];
            float4 a1 = Xl4[r * 32 + j + 8];
            float4 a2 = Xl4[r * 32 + j + 16];
            float4 a3 = Xl4[r * 32 + j + 24];
            float s = a0.x + a0.y + a0.z + a0.w + a1.x + a1.y + a1.z + a1.w
                    + a2.x + a2.y + a2.z + a2.w + a3.x + a3.y + a3.z + a3.w;
            s += __shfl_down(s, 4, 8);
            s += __shfl_down(s, 2, 8);
            s += __shfl_down(s, 1, 8);
            float tot = __shfl(s, 0, 8);
            float inv = tot > 0.f ? 1.f / tot : 0.f;
            a0.x *= inv; a0.y *= inv; a0.z *= inv; a0.w *= inv;
            a1.x *= inv; a1.y *= inv; a1.z *= inv; a1.w *= inv;
            a2.x *= inv; a2.y *= inv; a2.z *= inv; a2.w *= inv;
            a3.x *= inv; a3.y *= inv; a3.z *= inv; a3.w *= inv;
            Xl4[r * 32 + j] = a0;
            Xl4[r * 32 + j + 8] = a1;
            Xl4[r * 32 + j + 16] = a2;
            Xl4[r * 32 + j + 24] = a3;
            __syncthreads();
        }

        float acc[4][4] = {};
        for (int k = 0; k < D; k += 4) {
            float xv[4][4], wv[4][4];
            #pragma unroll
            for (int r = 0; r < 4; r++) {
                float4 v = *(const float4*)&Xl[(r0 + r) * D + k];
                xv[r][0] = v.x; xv[r][1] = v.y; xv[r][2] = v.z; xv[r][3] = v.w;
            }
            #pragma unroll
            for (int kk = 0; kk < 4; kk++) {
                float4 v = *(const float4*)&Wl[(k + kk) * D + c0];
                wv[kk][0] = v.x; wv[kk][1] = v.y; wv[kk][2] = v.z; wv[kk][3] = v.w;
            }
            #pragma unroll
            for (int r = 0; r < 4; r++)
                #pragma unroll
                for (int c = 0; c < 4; c++)
                    #pragma unroll
                    for (int kk = 0; kk < 4; kk++)
                        acc[r][c] += xv[r][kk] * wv[kk][c];
        }

        #pragma unroll
        for (int r = 0; r < 4; r++) {
            int row = rowbase + r0 + r;
            if (row < nrows) {
                float4 v;
                v.x = acc[r][0]; v.y = acc[r][1]; v.z = acc[r][2]; v.w = acc[r][3];
                *(float4*)&Y[(size_t)row * D + c0] = v;
            }
        }
    }
}

// ---------------- aggregation ----------------
// 2 nodes per wave: each 32-lane half owns a node; lane reads float4 (row =
// 32 lanes x 16B). Edge (src,norm) pairs loaded 8B-coalesced, broadcast via
// __shfl(width=32); gather unrolled 8x for MLP.

__global__ void k_agg(const float* __restrict__ Y, const int2* __restrict__ csr,
                      const int* __restrict__ start, const float* __restrict__ bias,
                      float* __restrict__ Out, int leaky, int N) {
    int wid = (blockIdx.x * blockDim.x + threadIdx.x) >> 6;
    int lane = threadIdx.x & 63;
    int half = lane >> 5;
    int l = lane & 31;
    int node = wid * 2 + half;
    bool valid = node < N;
    int s0 = valid ? start[node] : 0;
    int s1 = valid ? start[node + 1] : 0;
    int cnt = s1 - s0;

    float4 acc = {0.f, 0.f, 0.f, 0.f};
    const float4* Y4 = (const float4*)Y;

    for (int base = 0; base < cnt; base += 32) {
        int rem = cnt - base; if (rem > 32) rem = 32;
        int2 pr = (l < rem) ? csr[s0 + base + l] : make_int2(0, 0);
        int  sj = pr.x;
        float nj = __int_as_float(pr.y);
        int j = 0;
        for (; j + 8 <= rem; j += 8) {
            int   i0 = __shfl(sj, j + 0, 32), i1 = __shfl(sj, j + 1, 32);
            int   i2 = __shfl(sj, j + 2, 32), i3 = __shfl(sj, j + 3, 32);
            int   i4 = __shfl(sj, j + 4, 32), i5 = __shfl(sj, j + 5, 32);
            int   i6 = __shfl(sj, j + 6, 32), i7 = __shfl(sj, j + 7, 32);
            float n0 = __shfl(nj, j + 0, 32), n1 = __shfl(nj, j + 1, 32);
            float n2 = __shfl(nj, j + 2, 32), n3 = __shfl(nj, j + 3, 32);
            float n4 = __shfl(nj, j + 4, 32), n5 = __shfl(nj, j + 5, 32);
            float n6 = __shfl(nj, j + 6, 32), n7 = __shfl(nj, j + 7, 32);
            float4 v0 = Y4[(size_t)i0 * 32 + l];
            float4 v1 = Y4[(size_t)i1 * 32 + l];
            float4 v2 = Y4[(size_t)i2 * 32 + l];
            float4 v3 = Y4[(size_t)i3 * 32 + l];
            float4 v4 = Y4[(size_t)i4 * 32 + l];
            float4 v5 = Y4[(size_t)i5 * 32 + l];
            float4 v6 = Y4[(size_t)i6 * 32 + l];
            float4 v7 = Y4[(size_t)i7 * 32 + l];
            acc.x += n0 * v0.x; acc.y += n0 * v0.y; acc.z += n0 * v0.z; acc.w += n0 * v0.w;
            acc.x += n1 * v1.x; acc.y += n1 * v1.y; acc.z += n1 * v1.z; acc.w += n1 * v1.w;
            acc.x += n2 * v2.x; acc.y += n2 * v2.y; acc.z += n2 * v2.z; acc.w += n2 * v2.w;
            acc.x += n3 * v3.x; acc.y += n3 * v3.y; acc.z += n3 * v3.z; acc.w += n3 * v3.w;
            acc.x += n4 * v4.x; acc.y += n4 * v4.y; acc.z += n4 * v4.z; acc.w += n4 * v4.w;
            acc.x += n5 * v5.x; acc.y += n5 * v5.y; acc.z += n5 * v5.z; acc.w += n5 * v5.w;
            acc.x += n6 * v6.x; acc.y += n6 * v6.y; acc.z += n6 * v6.z; acc.w += n6 * v6.w;
            acc.x += n7 * v7.x; acc.y += n7 * v7.y; acc.z += n7 * v7.z; acc.w += n7 * v7.w;
        }
        for (; j + 4 <= rem; j += 4) {
            int   i0 = __shfl(sj, j + 0, 32), i1 = __shfl(sj, j + 1, 32);
            int   i2 = __shfl(sj, j + 2, 32), i3 = __shfl(sj, j + 3, 32);
            float n0 = __shfl(nj, j + 0, 32), n1 = __shfl(nj, j + 1, 32);
            float n2 = __shfl(nj, j + 2, 32), n3 = __shfl(nj, j + 3, 32);
            float4 v0 = Y4[(size_t)i0 * 32 + l];
            float4 v1 = Y4[(size_t)i1 * 32 + l];
            float4 v2 = Y4[(size_t)i2 * 32 + l];
            float4 v3 = Y4[(size_t)i3 * 32 + l];
            acc.x += n0 * v0.x; acc.y += n0 * v0.y; acc.z += n0 * v0.z; acc.w += n0 * v0.w;
            acc.x += n1 * v1.x; acc.y += n1 * v1.y; acc.z += n1 * v1.z; acc.w += n1 * v1.w;
            acc.x += n2 * v2.x; acc.y += n2 * v2.y; acc.z += n2 * v2.z; acc.w += n2 * v2.w;
            acc.x += n3 * v3.x; acc.y += n3 * v3.y; acc.z += n3 * v3.z; acc.w += n3 * v3.w;
        }
        for (; j < rem; j++) {
            int   i0 = __shfl(sj, j, 32);
            float n0 = __shfl(nj, j, 32);
            float4 v0 = Y4[(size_t)i0 * 32 + l];
            acc.x += n0 * v0.x; acc.y += n0 * v0.y; acc.z += n0 * v0.z; acc.w += n0 * v0.w;
        }
    }

    if (!valid) return;
    float4 b4 = ((const float4*)bias)[l];
    float4 v;
    v.x = acc.x + b4.x; v.y = acc.y + b4.y; v.z = acc.z + b4.z; v.w = acc.w + b4.w;
    if (leaky) {
        v.x = v.x > 0.f ? v.x : LEAKY * v.x;
        v.y = v.y > 0.f ? v.y : LEAKY * v.y;
        v.z = v.z > 0.f ? v.z : LEAKY * v.z;
        v.w = v.w > 0.f ? v.w : LEAKY * v.w;
    }
    ((float4*)Out)[(size_t)node * 32 + l] = v;
}

// ---------------- launch ----------------

extern "C" void kernel_launch(void* const* d_in, const int* in_sizes, int n_in,
                              void* d_out, int out_size, void* d_ws, size_t ws_size,
                              hipStream_t stream) {
    const float* feat = (const float*)d_in[0];
    const int*   eidx = (const int*)d_in[1];
    const float* ew   = (const float*)d_in[2];
    const float* W1   = (const float*)d_in[3];
    const float* b1   = (const float*)d_in[4];
    const float* W2   = (const float*)d_in[5];
    const float* b2   = (const float*)d_in[6];
    const float* W3   = (const float*)d_in[7];
    const float* b3   = (const float*)d_in[8];

    const int N = in_sizes[0] / D;   // 50000
    const int E = in_sizes[2];       // 600000
    const int* src = eidx;
    const int* dst = eidx + E;

    // workspace layout (4B units); total ~33.6 MB
    size_t off = 0;
    char* base = (char*)d_ws;
    auto alloc4 = [&](size_t elems) -> void* {
        void* p = base + off * 4;
        off += (elems + 3) & ~(size_t)3;
        return p;
    };
    float* rowsum   = (float*)alloc4(N);      // zeroed
    int*   cnt      = (int*)  alloc4(N);      // zeroed (contiguous with rowsum)
    char*  zero_end = base + off * 4;
    int*   start    = (int*)  alloc4(N + 1);
    float* dinv     = (float*)alloc4(N);
    int*   partial  = (int*)  alloc4(64);
    int*   rank     = (int*)  alloc4(E);
    int2*  csr      = (int2*) alloc4((size_t)E * 2);
    float* xbuf     = (float*)alloc4((size_t)N * D);
    float* outp     = (float*)d_out;

    hipMemsetAsync(rowsum, 0, (size_t)(zero_end - (char*)rowsum), stream);

    int eblocks  = (E + 255) / 256;
    int eblocks4 = (E + 1023) / 1024;
    int nchunks  = (N + SCAN_CHUNK - 1) / SCAN_CHUNK;
    int nblocks  = (N + 255) / 256;
    int cblocks  = ((size_t)N * 16 + 255) / 256;   // k_csr_norm: 16 lanes/node
    int ablocks  = ((N + 1) / 2 * 64 + 255) / 256; // k_agg: 2 nodes per wave
    int gblocks  = (N + GEMM_ROWS * GTILES - 1) / (GEMM_ROWS * GTILES);

    k_pass1<<<eblocks4, 256, 0, stream>>>(src, dst, ew, rowsum, cnt, rank, E);

    k_chunk_sum<<<nchunks, 256, 0, stream>>>(cnt, partial, N);
    k_scan_partial<<<1, 64, 0, stream>>>(partial, nchunks);
    k_chunk_scan<<<nchunks, 256, 0, stream>>>(cnt, partial, start, N, E);

    k_scatter2<<<eblocks, 256, 0, stream>>>(src, dst, ew, rowsum, start, rank, csr, E);
    k_deg_dinv<<<nblocks, 256, 0, stream>>>(csr, start, dinv, N);
    k_csr_norm<<<cblocks, 256, 0, stream>>>(csr, start, dinv, N);

    // layer 1: gemm feat->xbuf with fused row-normalize, agg xbuf->out (leaky)
    k_gemm<<<gblocks, 256, 0, stream>>>(feat, W1, xbuf, N, 1);
    k_agg<<<ablocks, 256, 0, stream>>>(xbuf, csr, start, b1, outp, 1, N);
    // layer 2: gemm in-place out->out, agg out->x (leaky)
    k_gemm<<<gblocks, 256, 0, stream>>>(outp, W2, outp, N, 0);
    k_agg<<<ablocks, 256, 0, stream>>>(outp, csr, start, b2, xbuf, 1, N);
    // layer 3: gemm in-place x->x, agg x->out (no activation)
    k_gemm<<<gblocks, 256, 0, stream>>>(xbuf, W3, xbuf, N, 0);
    k_agg<<<ablocks, 256, 0, stream>>>(xbuf, csr, start, b3, outp, 0, N);
}

// Round 6
// 335.668 us; speedup vs baseline: 1.6066x; 1.2976x over previous
//
#include <hip/hip_runtime.h>

#define D 128
#define LEAKY 0.01f
#define SCAN_CHUNK 2048   // 256 threads x 8 elements

typedef __attribute__((ext_vector_type(8))) short short8;
typedef __attribute__((ext_vector_type(4))) float f32x4;

__device__ __forceinline__ unsigned short f2bf(float f) {
    unsigned u = __float_as_uint(f);
    u += 0x7fffu + ((u >> 16) & 1u);          // round-to-nearest-even
    return (unsigned short)(u >> 16);
}

// ---------------- pass 1: rowsum over src (atomic) + dst histogram w/ rank ----------------
// 1 edge/thread (best measured shape: atomic-RMW throughput bound, needs max waves)

__global__ void k_pass1(const int* __restrict__ src, const int* __restrict__ dst,
                        const float* __restrict__ w, float* __restrict__ rowsum,
                        int* __restrict__ cnt, int* __restrict__ rank, int E) {
    int e = blockIdx.x * 256 + threadIdx.x;
    if (e >= E) return;
    atomicAdd(&rowsum[src[e]], w[e]);
    rank[e] = atomicAdd(&cnt[dst[e]], 1);
}

// ---------------- prefix scan (3-phase) over cnt[N] -> start[N+1] ----------------

__global__ void k_chunk_sum(const int* __restrict__ cnt, int* __restrict__ partial, int n) {
    __shared__ int sdata[256];
    int b = blockIdx.x;
    int base = b * SCAN_CHUNK;
    int s = 0;
    for (int i = threadIdx.x; i < SCAN_CHUNK; i += 256) {
        int idx = base + i;
        s += (idx < n) ? cnt[idx] : 0;
    }
    sdata[threadIdx.x] = s;
    __syncthreads();
    for (int off = 128; off > 0; off >>= 1) {
        if (threadIdx.x < off) sdata[threadIdx.x] += sdata[threadIdx.x + off];
        __syncthreads();
    }
    if (threadIdx.x == 0) partial[b] = sdata[0];
}

__global__ void k_scan_partial(int* __restrict__ partial, int nchunks) {
    if (blockIdx.x == 0 && threadIdx.x == 0) {
        int run = 0;
        for (int i = 0; i < nchunks; i++) { int v = partial[i]; partial[i] = run; run += v; }
    }
}

__global__ void k_chunk_scan(const int* __restrict__ cnt, const int* __restrict__ partial,
                             int* __restrict__ start, int n, int total) {
    __shared__ int sdata[256];
    int b = blockIdx.x;
    int base = b * SCAN_CHUNK;
    int t = threadIdx.x;
    int loc[8];
    int s = 0;
    int tb = base + t * 8;
    #pragma unroll
    for (int j = 0; j < 8; j++) {
        int idx = tb + j;
        int v = (idx < n) ? cnt[idx] : 0;
        loc[j] = s;
        s += v;
    }
    sdata[t] = s;
    __syncthreads();
    for (int off = 1; off < 256; off <<= 1) {
        int v = (t >= off) ? sdata[t - off] : 0;
        __syncthreads();
        sdata[t] += v;
        __syncthreads();
    }
    int texcl = (t == 0) ? 0 : sdata[t - 1];
    int offb = partial[b];
    #pragma unroll
    for (int j = 0; j < 8; j++) {
        int idx = tb + j;
        if (idx < n) start[idx] = offb + texcl + loc[j];
    }
    if (b == gridDim.x - 1 && t == 255) start[n] = total;
}

// ---------------- scatter (NO atomics): compute w_hat, place at start[d]+rank[e] ----------------

__global__ void k_scatter2(const int* __restrict__ src, const int* __restrict__ dst,
                           const float* __restrict__ w, const float* __restrict__ rowsum,
                           const int* __restrict__ start, const int* __restrict__ rank,
                           int2* __restrict__ csr, int E) {
    int e = blockIdx.x * 256 + threadIdx.x;
    if (e >= E) return;
    int s = src[e], d = dst[e];
    float rs = rowsum[s], rd = rowsum[d];
    float wh = w[e] * (rs > 0.f ? 1.f / rs : 0.f) * (rd > 0.f ? 1.f / rd : 0.f);
    int idx = start[d] + rank[e];
    csr[idx] = make_int2(s, __float_as_int(wh));
}

// ---------------- deg via contiguous segment gather (no atomics) -> dinv ----------------

__global__ void k_deg_dinv(const int2* __restrict__ csr, const int* __restrict__ start,
                           float* __restrict__ dinv, int N) {
    int n = blockIdx.x * 256 + threadIdx.x;
    if (n >= N) return;
    int s0 = start[n], s1 = start[n + 1];
    float s = 0.f;
    for (int i = s0; i < s1; i++) s += __int_as_float(csr[i].y);
    dinv[n] = s > 0.f ? rsqrtf(s) : 0.f;
}

// ---------------- finalize norm in place: csr[i].wh *= dinv[src]*dinv[dstnode] ----------------

__global__ void k_csr_norm(int2* __restrict__ csr, const int* __restrict__ start,
                           const float* __restrict__ dinv, int N) {
    int g = (blockIdx.x * blockDim.x + threadIdx.x) >> 4;
    int l = threadIdx.x & 15;
    if (g >= N) return;
    int s0 = start[g], s1 = start[g + 1];
    float dd = dinv[g];
    for (int i = s0 + l; i < s1; i += 16) {
        int2 p = csr[i];
        float nm = __int_as_float(p.y) * dinv[p.x] * dd;
        csr[i] = make_int2(p.x, __float_as_int(nm));
    }
}

// ---------------- feature row-normalize: xb = bf16( feat / rowsum(feat) ) ----------------

__global__ void k_norm_feat(const float* __restrict__ feat, unsigned short* __restrict__ xb,
                            int N) {
    int node = (blockIdx.x * blockDim.x + threadIdx.x) >> 6;
    int lane = threadIdx.x & 63;
    if (node >= N) return;
    const float* f = feat + (size_t)node * D;
    float a = f[lane], b = f[lane + 64];
    float s = a + b;
    #pragma unroll
    for (int off = 32; off > 0; off >>= 1) s += __shfl_down(s, off);
    s = __shfl(s, 0);
    float inv = 1.0f / s;
    xb[(size_t)node * D + lane] = f2bf(a * inv);
    xb[(size_t)node * D + 64 + lane] = f2bf(b * inv);
}

// ---------------- MFMA GEMM: Yb[N,128](bf16) = Xb[N,128](bf16) @ W[128,128](f32->bf16) ----------------
// 256 thr = 4 waves, 64 rows/block. W transposed to LDS [col][k] bf16, XOR-swizzled
// (byte ^= (row&7)<<4) so A/B fragment ds_read_b128 are conflict-free.
// mfma_f32_16x16x32_bf16: A row=l&15, k=(l>>4)*8+j ; B col=l&15, same k ;
// D row=(l>>4)*4+j, col=l&15  (guide §3, m89-verified).
// In-place safe (Yb may alias Xb): block stages its rows to LDS before writing.

#define GR 64

__global__ __launch_bounds__(256) void k_gemm_mfma(const unsigned short* __restrict__ Xb,
                                                   const float* __restrict__ W,
                                                   unsigned short* __restrict__ Yb, int nrows) {
    __shared__ unsigned short Wt[128 * 128];   // 32KB: [col][k] bf16, swizzled
    __shared__ unsigned short Xs[GR * 128];    // 16KB: [row][k] bf16, swizzled
    int t = threadIdx.x;

    // stage W: coalesced f32 read of W[k][col]; swizzled bf16 write to Wt[col][k]
    for (int i = t; i < 128 * 128; i += 256) {
        int k = i >> 7, col = i & 127;
        unsigned short h = f2bf(W[i]);
        int byte = col * 256 + ((k * 2) ^ ((col & 7) << 4));
        *(unsigned short*)((char*)Wt + byte) = h;
    }
    // stage X tile: 16B chunks, coalesced; swizzled LDS write
    int rowbase = blockIdx.x * GR;
    for (int i = t; i < GR * 16; i += 256) {
        int r = i >> 4, c = i & 15;
        uint4 v = {0u, 0u, 0u, 0u};
        int row = rowbase + r;
        if (row < nrows) v = *(const uint4*)(Xb + (size_t)row * 128 + c * 8);
        int byte = r * 256 + ((c * 16) ^ ((r & 7) << 4));
        *(uint4*)((char*)Xs + byte) = v;
    }
    __syncthreads();

    int w = t >> 6, l = t & 63;
    int r0 = w * 16;
    int lr = l & 15, lg = l >> 4;

    short8 a[4];
    {
        int row = r0 + lr;
        const char* rp = (const char*)Xs + row * 256;
        int sw = (row & 7) << 4;
        #pragma unroll
        for (int s = 0; s < 4; s++)
            a[s] = *(const short8*)(rp + ((s * 64 + lg * 16) ^ sw));
    }

    f32x4 acc[8];
    #pragma unroll
    for (int ct = 0; ct < 8; ct++) {
        f32x4 c = {0.f, 0.f, 0.f, 0.f};
        int col = ct * 16 + lr;
        const char* cp = (const char*)Wt + col * 256;
        int sw = (col & 7) << 4;
        #pragma unroll
        for (int s = 0; s < 4; s++) {
            short8 b = *(const short8*)(cp + ((s * 64 + lg * 16) ^ sw));
            c = __builtin_amdgcn_mfma_f32_16x16x32_bf16(a[s], b, c, 0, 0, 0);
        }
        acc[ct] = c;
    }

    #pragma unroll
    for (int j = 0; j < 4; j++) {
        int row = rowbase + r0 + lg * 4 + j;
        if (row < nrows) {
            #pragma unroll
            for (int ct = 0; ct < 8; ct++)
                Yb[(size_t)row * 128 + ct * 16 + lr] = f2bf(acc[ct][j]);
        }
    }
}

// ---------------- aggregation (bf16 gather, f32 accum) ----------------
// 2 nodes/wave; lane (0..31) owns cols 4l..4l+3 (one uint2 = 4 bf16 per row).
// final=0: leaky + bf16 out ; final=1: no act + f32 out (d_out).

__device__ __forceinline__ void fma_row(float4& acc, float n, uint2 v) {
    acc.x += n * __uint_as_float(v.x << 16);
    acc.y += n * __uint_as_float(v.x & 0xffff0000u);
    acc.z += n * __uint_as_float(v.y << 16);
    acc.w += n * __uint_as_float(v.y & 0xffff0000u);
}

__global__ void k_agg(const unsigned short* __restrict__ Yb, const int2* __restrict__ csr,
                      const int* __restrict__ start, const float* __restrict__ bias,
                      unsigned short* __restrict__ OutB, float* __restrict__ OutF,
                      int final_, int N) {
    int wid = (blockIdx.x * blockDim.x + threadIdx.x) >> 6;
    int lane = threadIdx.x & 63;
    int half = lane >> 5;
    int l = lane & 31;
    int node = wid * 2 + half;
    bool valid = node < N;
    int s0 = valid ? start[node] : 0;
    int s1 = valid ? start[node + 1] : 0;
    int cnt = s1 - s0;

    float4 acc = {0.f, 0.f, 0.f, 0.f};
    const uint2* Y2 = (const uint2*)Yb;

    for (int base = 0; base < cnt; base += 32) {
        int rem = cnt - base; if (rem > 32) rem = 32;
        int2 pr = (l < rem) ? csr[s0 + base + l] : make_int2(0, 0);
        int  sj = pr.x;
        float nj = __int_as_float(pr.y);
        int j = 0;
        for (; j + 8 <= rem; j += 8) {
            int   i0 = __shfl(sj, j + 0, 32), i1 = __shfl(sj, j + 1, 32);
            int   i2 = __shfl(sj, j + 2, 32), i3 = __shfl(sj, j + 3, 32);
            int   i4 = __shfl(sj, j + 4, 32), i5 = __shfl(sj, j + 5, 32);
            int   i6 = __shfl(sj, j + 6, 32), i7 = __shfl(sj, j + 7, 32);
            float n0 = __shfl(nj, j + 0, 32), n1 = __shfl(nj, j + 1, 32);
            float n2 = __shfl(nj, j + 2, 32), n3 = __shfl(nj, j + 3, 32);
            float n4 = __shfl(nj, j + 4, 32), n5 = __shfl(nj, j + 5, 32);
            float n6 = __shfl(nj, j + 6, 32), n7 = __shfl(nj, j + 7, 32);
            uint2 v0 = Y2[(size_t)i0 * 32 + l];
            uint2 v1 = Y2[(size_t)i1 * 32 + l];
            uint2 v2 = Y2[(size_t)i2 * 32 + l];
            uint2 v3 = Y2[(size_t)i3 * 32 + l];
            uint2 v4 = Y2[(size_t)i4 * 32 + l];
            uint2 v5 = Y2[(size_t)i5 * 32 + l];
            uint2 v6 = Y2[(size_t)i6 * 32 + l];
            uint2 v7 = Y2[(size_t)i7 * 32 + l];
            fma_row(acc, n0, v0); fma_row(acc, n1, v1);
            fma_row(acc, n2, v2); fma_row(acc, n3, v3);
            fma_row(acc, n4, v4); fma_row(acc, n5, v5);
            fma_row(acc, n6, v6); fma_row(acc, n7, v7);
        }
        for (; j + 4 <= rem; j += 4) {
            int   i0 = __shfl(sj, j + 0, 32), i1 = __shfl(sj, j + 1, 32);
            int   i2 = __shfl(sj, j + 2, 32), i3 = __shfl(sj, j + 3, 32);
            float n0 = __shfl(nj, j + 0, 32), n1 = __shfl(nj, j + 1, 32);
            float n2 = __shfl(nj, j + 2, 32), n3 = __shfl(nj, j + 3, 32);
            uint2 v0 = Y2[(size_t)i0 * 32 + l];
            uint2 v1 = Y2[(size_t)i1 * 32 + l];
            uint2 v2 = Y2[(size_t)i2 * 32 + l];
            uint2 v3 = Y2[(size_t)i3 * 32 + l];
            fma_row(acc, n0, v0); fma_row(acc, n1, v1);
            fma_row(acc, n2, v2); fma_row(acc, n3, v3);
        }
        for (; j < rem; j++) {
            int   i0 = __shfl(sj, j, 32);
            float n0 = __shfl(nj, j, 32);
            uint2 v0 = Y2[(size_t)i0 * 32 + l];
            fma_row(acc, n0, v0);
        }
    }

    if (!valid) return;
    float4 b4 = ((const float4*)bias)[l];
    float4 v;
    v.x = acc.x + b4.x; v.y = acc.y + b4.y; v.z = acc.z + b4.z; v.w = acc.w + b4.w;
    if (final_) {
        ((float4*)OutF)[(size_t)node * 32 + l] = v;
    } else {
        v.x = v.x > 0.f ? v.x : LEAKY * v.x;
        v.y = v.y > 0.f ? v.y : LEAKY * v.y;
        v.z = v.z > 0.f ? v.z : LEAKY * v.z;
        v.w = v.w > 0.f ? v.w : LEAKY * v.w;
        uint2 o;
        o.x = (unsigned)f2bf(v.x) | ((unsigned)f2bf(v.y) << 16);
        o.y = (unsigned)f2bf(v.z) | ((unsigned)f2bf(v.w) << 16);
        ((uint2*)OutB)[(size_t)node * 32 + l] = o;
    }
}

// ---------------- launch ----------------

extern "C" void kernel_launch(void* const* d_in, const int* in_sizes, int n_in,
                              void* d_out, int out_size, void* d_ws, size_t ws_size,
                              hipStream_t stream) {
    const float* feat = (const float*)d_in[0];
    const int*   eidx = (const int*)d_in[1];
    const float* ew   = (const float*)d_in[2];
    const float* W1   = (const float*)d_in[3];
    const float* b1   = (const float*)d_in[4];
    const float* W2   = (const float*)d_in[5];
    const float* b2   = (const float*)d_in[6];
    const float* W3   = (const float*)d_in[7];
    const float* b3   = (const float*)d_in[8];

    const int N = in_sizes[0] / D;   // 50000
    const int E = in_sizes[2];       // 600000
    const int* src = eidx;
    const int* dst = eidx + E;

    // workspace layout (4B units); total ~33.6 MB
    size_t off = 0;
    char* base = (char*)d_ws;
    auto alloc4 = [&](size_t elems) -> void* {
        void* p = base + off * 4;
        off += (elems + 3) & ~(size_t)3;
        return p;
    };
    float* rowsum = (float*)alloc4(N);      // zeroed
    int*   cnt    = (int*)  alloc4(N);      // zeroed (contiguous with rowsum)
    char*  zero_end = base + off * 4;
    int*   start  = (int*)  alloc4(N + 1);
    float* dinv   = (float*)alloc4(N);
    int*   partial= (int*)  alloc4(64);
    int*   rank   = (int*)  alloc4(E);
    int2*  csr    = (int2*) alloc4((size_t)E * 2);
    unsigned short* xb = (unsigned short*)alloc4((size_t)N * 64);  // N x 128 bf16
    unsigned short* yb = (unsigned short*)alloc4((size_t)N * 64);
    float* outp = (float*)d_out;

    hipMemsetAsync(rowsum, 0, (size_t)(zero_end - (char*)rowsum), stream);

    int eblocks = (E + 255) / 256;
    int nchunks = (N + SCAN_CHUNK - 1) / SCAN_CHUNK;
    int nblocks = (N + 255) / 256;
    int cblocks = ((size_t)N * 16 + 255) / 256;   // k_csr_norm: 16 lanes/node
    int ablocks = ((N + 1) / 2 * 64 + 255) / 256; // k_agg: 2 nodes per wave
    int wblocks = (N + 3) / 4;                    // k_norm_feat: wave per node
    int gblocks = (N + GR - 1) / GR;

    k_pass1<<<eblocks, 256, 0, stream>>>(src, dst, ew, rowsum, cnt, rank, E);

    k_chunk_sum<<<nchunks, 256, 0, stream>>>(cnt, partial, N);
    k_scan_partial<<<1, 64, 0, stream>>>(partial, nchunks);
    k_chunk_scan<<<nchunks, 256, 0, stream>>>(cnt, partial, start, N, E);

    k_scatter2<<<eblocks, 256, 0, stream>>>(src, dst, ew, rowsum, start, rank, csr, E);
    k_deg_dinv<<<nblocks, 256, 0, stream>>>(csr, start, dinv, N);
    k_csr_norm<<<cblocks, 256, 0, stream>>>(csr, start, dinv, N);

    k_norm_feat<<<wblocks, 256, 0, stream>>>(feat, xb, N);

    // L1: gemm xb->xb (in-place), agg xb->yb (leaky, bf16)
    k_gemm_mfma<<<gblocks, 256, 0, stream>>>(xb, W1, xb, N);
    k_agg<<<ablocks, 256, 0, stream>>>(xb, csr, start, b1, yb, nullptr, 0, N);
    // L2: gemm yb->yb, agg yb->xb (leaky, bf16)
    k_gemm_mfma<<<gblocks, 256, 0, stream>>>(yb, W2, yb, N);
    k_agg<<<ablocks, 256, 0, stream>>>(yb, csr, start, b2, xb, nullptr, 0, N);
    // L3: gemm xb->xb, agg xb->d_out (no act, f32)
    k_gemm_mfma<<<gblocks, 256, 0, stream>>>(xb, W3, xb, N);
    k_agg<<<ablocks, 256, 0, stream>>>(xb, csr, start, b3, nullptr, outp, 1, N);
}

// Round 7
// 333.765 us; speedup vs baseline: 1.6157x; 1.0057x over previous
//
#include <hip/hip_runtime.h>

#define D 128
#define LEAKY 0.01f
#define SCAN_CHUNK 2048   // 256 threads x 8 elements

typedef __attribute__((ext_vector_type(8))) short short8;
typedef __attribute__((ext_vector_type(4))) float f32x4;

__device__ __forceinline__ unsigned short f2bf(float f) {
    unsigned u = __float_as_uint(f);
    u += 0x7fffu + ((u >> 16) & 1u);          // round-to-nearest-even
    return (unsigned short)(u >> 16);
}

// ---------------- pass 1: rowsum over src (atomic) + dst histogram w/ rank ----------------
// 1 edge/thread; floor = memory-side atomic RMW throughput (~17G/s), measured r5/r6.

__global__ void k_pass1(const int* __restrict__ src, const int* __restrict__ dst,
                        const float* __restrict__ w, float* __restrict__ rowsum,
                        int* __restrict__ cnt, int* __restrict__ rank, int E) {
    int e = blockIdx.x * 256 + threadIdx.x;
    if (e >= E) return;
    atomicAdd(&rowsum[src[e]], w[e]);
    rank[e] = atomicAdd(&cnt[dst[e]], 1);
}

// ---------------- prefix scan (3-phase) over cnt[N] -> start[N+1] ----------------

__global__ void k_chunk_sum(const int* __restrict__ cnt, int* __restrict__ partial, int n) {
    __shared__ int sdata[256];
    int b = blockIdx.x;
    int base = b * SCAN_CHUNK;
    int s = 0;
    for (int i = threadIdx.x; i < SCAN_CHUNK; i += 256) {
        int idx = base + i;
        s += (idx < n) ? cnt[idx] : 0;
    }
    sdata[threadIdx.x] = s;
    __syncthreads();
    for (int off = 128; off > 0; off >>= 1) {
        if (threadIdx.x < off) sdata[threadIdx.x] += sdata[threadIdx.x + off];
        __syncthreads();
    }
    if (threadIdx.x == 0) partial[b] = sdata[0];
}

__global__ void k_scan_partial(int* __restrict__ partial, int nchunks) {
    if (blockIdx.x == 0 && threadIdx.x == 0) {
        int run = 0;
        for (int i = 0; i < nchunks; i++) { int v = partial[i]; partial[i] = run; run += v; }
    }
}

__global__ void k_chunk_scan(const int* __restrict__ cnt, const int* __restrict__ partial,
                             int* __restrict__ start, int n, int total) {
    __shared__ int sdata[256];
    int b = blockIdx.x;
    int base = b * SCAN_CHUNK;
    int t = threadIdx.x;
    int loc[8];
    int s = 0;
    int tb = base + t * 8;
    #pragma unroll
    for (int j = 0; j < 8; j++) {
        int idx = tb + j;
        int v = (idx < n) ? cnt[idx] : 0;
        loc[j] = s;
        s += v;
    }
    sdata[t] = s;
    __syncthreads();
    for (int off = 1; off < 256; off <<= 1) {
        int v = (t >= off) ? sdata[t - off] : 0;
        __syncthreads();
        sdata[t] += v;
        __syncthreads();
    }
    int texcl = (t == 0) ? 0 : sdata[t - 1];
    int offb = partial[b];
    #pragma unroll
    for (int j = 0; j < 8; j++) {
        int idx = tb + j;
        if (idx < n) start[idx] = offb + texcl + loc[j];
    }
    if (b == gridDim.x - 1 && t == 255) start[n] = total;
}

// ---------------- scatter (NO atomics): compute w_hat, place at start[d]+rank[e] ----------------

__global__ void k_scatter2(const int* __restrict__ src, const int* __restrict__ dst,
                           const float* __restrict__ w, const float* __restrict__ rowsum,
                           const int* __restrict__ start, const int* __restrict__ rank,
                           int2* __restrict__ csr, int E) {
    int e = blockIdx.x * 256 + threadIdx.x;
    if (e >= E) return;
    int s = src[e], d = dst[e];
    float rs = rowsum[s], rd = rowsum[d];
    float wh = w[e] * (rs > 0.f ? 1.f / rs : 0.f) * (rd > 0.f ? 1.f / rd : 0.f);
    int idx = start[d] + rank[e];
    csr[idx] = make_int2(s, __float_as_int(wh));
}

// ---------------- deg via contiguous segment gather (no atomics) -> dinv ----------------

__global__ void k_deg_dinv(const int2* __restrict__ csr, const int* __restrict__ start,
                           float* __restrict__ dinv, int N) {
    int n = blockIdx.x * 256 + threadIdx.x;
    if (n >= N) return;
    int s0 = start[n], s1 = start[n + 1];
    float s = 0.f;
    for (int i = s0; i < s1; i++) s += __int_as_float(csr[i].y);
    dinv[n] = s > 0.f ? rsqrtf(s) : 0.f;
}

// ---------------- finalize norm in place: csr[i].wh *= dinv[src]*dinv[dstnode] ----------------

__global__ void k_csr_norm(int2* __restrict__ csr, const int* __restrict__ start,
                           const float* __restrict__ dinv, int N) {
    int g = (blockIdx.x * blockDim.x + threadIdx.x) >> 4;
    int l = threadIdx.x & 15;
    if (g >= N) return;
    int s0 = start[g], s1 = start[g + 1];
    float dd = dinv[g];
    for (int i = s0 + l; i < s1; i += 16) {
        int2 p = csr[i];
        float nm = __int_as_float(p.y) * dinv[p.x] * dd;
        csr[i] = make_int2(p.x, __float_as_int(nm));
    }
}

// ---------------- MFMA GEMM: Yb[N,128](bf16) = X[N,128] @ W[128,128] ----------------
// 256 thr = 4 waves, 64 rows/block. W transposed to LDS [col][k] bf16, XOR-swizzled
// (byte ^= (row&7)<<4) -> conflict-free ds_read_b128 fragments.
// DO_NORM=1 (layer 1): X read as f32 from feat, row-normalized in registers
// (4 threads/row, shfl width-4 reduce), converted to bf16, written swizzled.
// DO_NORM=0: X read as bf16 (in-place safe: block stages its rows pre-write).

#define GR 64

template<int DO_NORM>
__global__ __launch_bounds__(256) void k_gemm_mfma(const float* __restrict__ Xf32,
                                                   const unsigned short* __restrict__ Xb,
                                                   const float* __restrict__ W,
                                                   unsigned short* __restrict__ Yb, int nrows) {
    __shared__ unsigned short Wt[128 * 128];   // 32KB: [col][k] bf16, swizzled
    __shared__ unsigned short Xs[GR * 128];    // 16KB: [row][k] bf16, swizzled
    int t = threadIdx.x;
    int rowbase = blockIdx.x * GR;

    // stage W: coalesced f32 read of W[k][col]; swizzled bf16 write to Wt[col][k]
    for (int i = t; i < 128 * 128; i += 256) {
        int k = i >> 7, col = i & 127;
        unsigned short h = f2bf(W[i]);
        int byte = col * 256 + ((k * 2) ^ ((col & 7) << 4));
        *(unsigned short*)((char*)Wt + byte) = h;
    }

    if (DO_NORM) {
        // 4 threads per row; thread q owns float4s {q, q+4, ..., q+28} (coalesced per k)
        int r = t >> 2, q = t & 3;
        int row = rowbase + r;
        const float4* Xr = (const float4*)(Xf32 + (size_t)row * 128);
        float4 v[8];
        float s = 0.f;
        #pragma unroll
        for (int k = 0; k < 8; k++) {
            float4 x = make_float4(0.f, 0.f, 0.f, 0.f);
            if (row < nrows) x = Xr[q + k * 4];
            v[k] = x;
            s += x.x + x.y + x.z + x.w;
        }
        s += __shfl_down(s, 2, 4);
        s += __shfl_down(s, 1, 4);
        float tot = __shfl(s, 0, 4);
        float inv = tot > 0.f ? 1.f / tot : 0.f;
        int sw = (r & 7) << 4;
        #pragma unroll
        for (int k = 0; k < 8; k++) {
            int gidx = q + k * 4;                  // float4 index 0..31 within row
            ushort4 h;
            h.x = f2bf(v[k].x * inv); h.y = f2bf(v[k].y * inv);
            h.z = f2bf(v[k].z * inv); h.w = f2bf(v[k].w * inv);
            // 8B granule at pre-swizzle byte gidx*8; XOR hits bits 4-6 only -> stays 8B-aligned
            *(ushort4*)((char*)Xs + r * 256 + ((gidx * 8) ^ sw)) = h;
        }
    } else {
        for (int i = t; i < GR * 16; i += 256) {
            int r = i >> 4, c = i & 15;
            uint4 vv = {0u, 0u, 0u, 0u};
            int row = rowbase + r;
            if (row < nrows) vv = *(const uint4*)(Xb + (size_t)row * 128 + c * 8);
            int byte = r * 256 + ((c * 16) ^ ((r & 7) << 4));
            *(uint4*)((char*)Xs + byte) = vv;
        }
    }
    __syncthreads();

    int w = t >> 6, l = t & 63;
    int r0 = w * 16;
    int lr = l & 15, lg = l >> 4;

    short8 a[4];
    {
        int row = r0 + lr;
        const char* rp = (const char*)Xs + row * 256;
        int sw = (row & 7) << 4;
        #pragma unroll
        for (int s = 0; s < 4; s++)
            a[s] = *(const short8*)(rp + ((s * 64 + lg * 16) ^ sw));
    }

    f32x4 acc[8];
    #pragma unroll
    for (int ct = 0; ct < 8; ct++) {
        f32x4 c = {0.f, 0.f, 0.f, 0.f};
        int col = ct * 16 + lr;
        const char* cp = (const char*)Wt + col * 256;
        int sw = (col & 7) << 4;
        #pragma unroll
        for (int s = 0; s < 4; s++) {
            short8 b = *(const short8*)(cp + ((s * 64 + lg * 16) ^ sw));
            c = __builtin_amdgcn_mfma_f32_16x16x32_bf16(a[s], b, c, 0, 0, 0);
        }
        acc[ct] = c;
    }

    #pragma unroll
    for (int j = 0; j < 4; j++) {
        int row = rowbase + r0 + lg * 4 + j;
        if (row < nrows) {
            #pragma unroll
            for (int ct = 0; ct < 8; ct++)
                Yb[(size_t)row * 128 + ct * 16 + lr] = f2bf(acc[ct][j]);
        }
    }
}

// ---------------- aggregation (bf16 gather, f32 accum) ----------------
// 4 nodes/wave: 16-lane groups; lane owns cols 8l..8l+7 (one uint4 = 8 bf16/row).
// (src,norm) loaded 16-coalesced, broadcast via __shfl(width=16); 8-deep MLP.
// final=0: leaky + bf16 out (one uint4 store) ; final=1: no act + f32 out.

__device__ __forceinline__ void fma8(float* acc, float n, uint4 v) {
    acc[0] += n * __uint_as_float(v.x << 16);
    acc[1] += n * __uint_as_float(v.x & 0xffff0000u);
    acc[2] += n * __uint_as_float(v.y << 16);
    acc[3] += n * __uint_as_float(v.y & 0xffff0000u);
    acc[4] += n * __uint_as_float(v.z << 16);
    acc[5] += n * __uint_as_float(v.z & 0xffff0000u);
    acc[6] += n * __uint_as_float(v.w << 16);
    acc[7] += n * __uint_as_float(v.w & 0xffff0000u);
}

__global__ void k_agg(const unsigned short* __restrict__ Yb, const int2* __restrict__ csr,
                      const int* __restrict__ start, const float* __restrict__ bias,
                      unsigned short* __restrict__ OutB, float* __restrict__ OutF,
                      int final_, int N) {
    int wid = (blockIdx.x * blockDim.x + threadIdx.x) >> 6;
    int lane = threadIdx.x & 63;
    int g = lane >> 4;
    int l = lane & 15;
    int node = wid * 4 + g;
    bool valid = node < N;
    int s0 = valid ? start[node] : 0;
    int s1 = valid ? start[node + 1] : 0;
    int cnt = s1 - s0;

    float acc[8] = {};
    const uint4* Y4 = (const uint4*)Yb;          // row = 16 uint4

    for (int base = 0; base < cnt; base += 16) {
        int rem = cnt - base; if (rem > 16) rem = 16;
        int2 pr = (l < rem) ? csr[s0 + base + l] : make_int2(0, 0);
        int  sj = pr.x;
        float nj = __int_as_float(pr.y);
        int j = 0;
        for (; j + 8 <= rem; j += 8) {
            int   i0 = __shfl(sj, j + 0, 16), i1 = __shfl(sj, j + 1, 16);
            int   i2 = __shfl(sj, j + 2, 16), i3 = __shfl(sj, j + 3, 16);
            int   i4 = __shfl(sj, j + 4, 16), i5 = __shfl(sj, j + 5, 16);
            int   i6 = __shfl(sj, j + 6, 16), i7 = __shfl(sj, j + 7, 16);
            float n0 = __shfl(nj, j + 0, 16), n1 = __shfl(nj, j + 1, 16);
            float n2 = __shfl(nj, j + 2, 16), n3 = __shfl(nj, j + 3, 16);
            float n4 = __shfl(nj, j + 4, 16), n5 = __shfl(nj, j + 5, 16);
            float n6 = __shfl(nj, j + 6, 16), n7 = __shfl(nj, j + 7, 16);
            uint4 v0 = Y4[(size_t)i0 * 16 + l];
            uint4 v1 = Y4[(size_t)i1 * 16 + l];
            uint4 v2 = Y4[(size_t)i2 * 16 + l];
            uint4 v3 = Y4[(size_t)i3 * 16 + l];
            uint4 v4 = Y4[(size_t)i4 * 16 + l];
            uint4 v5 = Y4[(size_t)i5 * 16 + l];
            uint4 v6 = Y4[(size_t)i6 * 16 + l];
            uint4 v7 = Y4[(size_t)i7 * 16 + l];
            fma8(acc, n0, v0); fma8(acc, n1, v1);
            fma8(acc, n2, v2); fma8(acc, n3, v3);
            fma8(acc, n4, v4); fma8(acc, n5, v5);
            fma8(acc, n6, v6); fma8(acc, n7, v7);
        }
        for (; j + 4 <= rem; j += 4) {
            int   i0 = __shfl(sj, j + 0, 16), i1 = __shfl(sj, j + 1, 16);
            int   i2 = __shfl(sj, j + 2, 16), i3 = __shfl(sj, j + 3, 16);
            float n0 = __shfl(nj, j + 0, 16), n1 = __shfl(nj, j + 1, 16);
            float n2 = __shfl(nj, j + 2, 16), n3 = __shfl(nj, j + 3, 16);
            uint4 v0 = Y4[(size_t)i0 * 16 + l];
            uint4 v1 = Y4[(size_t)i1 * 16 + l];
            uint4 v2 = Y4[(size_t)i2 * 16 + l];
            uint4 v3 = Y4[(size_t)i3 * 16 + l];
            fma8(acc, n0, v0); fma8(acc, n1, v1);
            fma8(acc, n2, v2); fma8(acc, n3, v3);
        }
        for (; j < rem; j++) {
            int   i0 = __shfl(sj, j, 16);
            float n0 = __shfl(nj, j, 16);
            uint4 v0 = Y4[(size_t)i0 * 16 + l];
            fma8(acc, n0, v0);
        }
    }

    if (!valid) return;
    float4 ba = ((const float4*)bias)[l * 2];
    float4 bb = ((const float4*)bias)[l * 2 + 1];
    float o[8];
    o[0] = acc[0] + ba.x; o[1] = acc[1] + ba.y; o[2] = acc[2] + ba.z; o[3] = acc[3] + ba.w;
    o[4] = acc[4] + bb.x; o[5] = acc[5] + bb.y; o[6] = acc[6] + bb.z; o[7] = acc[7] + bb.w;
    if (final_) {
        float4 w0 = {o[0], o[1], o[2], o[3]};
        float4 w1 = {o[4], o[5], o[6], o[7]};
        ((float4*)OutF)[(size_t)node * 32 + l * 2] = w0;
        ((float4*)OutF)[(size_t)node * 32 + l * 2 + 1] = w1;
    } else {
        #pragma unroll
        for (int k = 0; k < 8; k++) o[k] = o[k] > 0.f ? o[k] : LEAKY * o[k];
        uint4 ov;
        ov.x = (unsigned)f2bf(o[0]) | ((unsigned)f2bf(o[1]) << 16);
        ov.y = (unsigned)f2bf(o[2]) | ((unsigned)f2bf(o[3]) << 16);
        ov.z = (unsigned)f2bf(o[4]) | ((unsigned)f2bf(o[5]) << 16);
        ov.w = (unsigned)f2bf(o[6]) | ((unsigned)f2bf(o[7]) << 16);
        ((uint4*)OutB)[(size_t)node * 16 + l] = ov;
    }
}

// ---------------- launch ----------------

extern "C" void kernel_launch(void* const* d_in, const int* in_sizes, int n_in,
                              void* d_out, int out_size, void* d_ws, size_t ws_size,
                              hipStream_t stream) {
    const float* feat = (const float*)d_in[0];
    const int*   eidx = (const int*)d_in[1];
    const float* ew   = (const float*)d_in[2];
    const float* W1   = (const float*)d_in[3];
    const float* b1   = (const float*)d_in[4];
    const float* W2   = (const float*)d_in[5];
    const float* b2   = (const float*)d_in[6];
    const float* W3   = (const float*)d_in[7];
    const float* b3   = (const float*)d_in[8];

    const int N = in_sizes[0] / D;   // 50000
    const int E = in_sizes[2];       // 600000
    const int* src = eidx;
    const int* dst = eidx + E;

    // workspace layout (4B units)
    size_t off = 0;
    char* base = (char*)d_ws;
    auto alloc4 = [&](size_t elems) -> void* {
        void* p = base + off * 4;
        off += (elems + 3) & ~(size_t)3;
        return p;
    };
    float* rowsum = (float*)alloc4(N);      // zeroed
    int*   cnt    = (int*)  alloc4(N);      // zeroed (contiguous with rowsum)
    char*  zero_end = base + off * 4;
    int*   start  = (int*)  alloc4(N + 1);
    float* dinv   = (float*)alloc4(N);
    int*   partial= (int*)  alloc4(64);
    int*   rank   = (int*)  alloc4(E);
    int2*  csr    = (int2*) alloc4((size_t)E * 2);
    unsigned short* xb = (unsigned short*)alloc4((size_t)N * 64);  // N x 128 bf16
    unsigned short* yb = (unsigned short*)alloc4((size_t)N * 64);
    float* outp = (float*)d_out;

    hipMemsetAsync(rowsum, 0, (size_t)(zero_end - (char*)rowsum), stream);

    int eblocks = (E + 255) / 256;
    int nchunks = (N + SCAN_CHUNK - 1) / SCAN_CHUNK;
    int nblocks = (N + 255) / 256;
    int cblocks = ((size_t)N * 16 + 255) / 256;    // k_csr_norm: 16 lanes/node
    int ablocks = (((N + 3) / 4) * 64 + 255) / 256; // k_agg: 4 nodes per wave
    int gblocks = (N + GR - 1) / GR;

    k_pass1<<<eblocks, 256, 0, stream>>>(src, dst, ew, rowsum, cnt, rank, E);

    k_chunk_sum<<<nchunks, 256, 0, stream>>>(cnt, partial, N);
    k_scan_partial<<<1, 64, 0, stream>>>(partial, nchunks);
    k_chunk_scan<<<nchunks, 256, 0, stream>>>(cnt, partial, start, N, E);

    k_scatter2<<<eblocks, 256, 0, stream>>>(src, dst, ew, rowsum, start, rank, csr, E);
    k_deg_dinv<<<nblocks, 256, 0, stream>>>(csr, start, dinv, N);
    k_csr_norm<<<cblocks, 256, 0, stream>>>(csr, start, dinv, N);

    // L1: gemm feat->xb (fused row-normalize), agg xb->yb (leaky, bf16)
    k_gemm_mfma<1><<<gblocks, 256, 0, stream>>>(feat, nullptr, W1, xb, N);
    k_agg<<<ablocks, 256, 0, stream>>>(xb, csr, start, b1, yb, nullptr, 0, N);
    // L2: gemm yb->yb (in-place), agg yb->xb (leaky, bf16)
    k_gemm_mfma<0><<<gblocks, 256, 0, stream>>>(nullptr, yb, W2, yb, N);
    k_agg<<<ablocks, 256, 0, stream>>>(yb, csr, start, b2, xb, nullptr, 0, N);
    // L3: gemm xb->xb (in-place), agg xb->d_out (no act, f32)
    k_gemm_mfma<0><<<gblocks, 256, 0, stream>>>(nullptr, xb, W3, xb, N);
    k_agg<<<ablocks, 256, 0, stream>>>(xb, csr, start, b3, nullptr, outp, 1, N);
}

// Round 8
// 301.962 us; speedup vs baseline: 1.7859x; 1.1053x over previous
//
#include <hip/hip_runtime.h>

#define D 128
#define LEAKY 0.01f
#define SCAN_CHUNK 2048   // 256 threads x 8 elements

typedef __attribute__((ext_vector_type(8))) short short8;
typedef __attribute__((ext_vector_type(4))) float f32x4;

__device__ __forceinline__ unsigned short f2bf(float f) {
    unsigned u = __float_as_uint(f);
    u += 0x7fffu + ((u >> 16) & 1u);          // round-to-nearest-even
    return (unsigned short)(u >> 16);
}

// ---------------- W prep: f32 [k][col] -> bf16 [col][k], PRE-SWIZZLED ----------------
// Global layout matches the GEMM's LDS layout exactly (byte = col*256 + ((2k)^((col&7)<<4))),
// so GEMM staging is a plain linear uint4 copy. 3 matrices, 6144 threads.

__global__ void k_wprep(const float* __restrict__ W1, const float* __restrict__ W2,
                        const float* __restrict__ W3, unsigned short* __restrict__ wtg) {
    int tid = blockIdx.x * 256 + threadIdx.x;
    if (tid >= 3 * 128 * 16) return;
    int col = tid & 127;
    int s   = (tid >> 7) & 15;    // granule: 8 consecutive k
    int w   = tid >> 11;
    const float* Ws = (w == 0) ? W1 : (w == 1) ? W2 : W3;
    unsigned un[4];
    #pragma unroll
    for (int p = 0; p < 4; p++) {
        float a = Ws[(s * 8 + 2 * p) * 128 + col];
        float b = Ws[(s * 8 + 2 * p + 1) * 128 + col];
        un[p] = (unsigned)f2bf(a) | ((unsigned)f2bf(b) << 16);
    }
    uint4 v = {un[0], un[1], un[2], un[3]};
    int byte = w * 32768 + col * 256 + ((s * 16) ^ ((col & 7) << 4));
    *(uint4*)((char*)wtg + byte) = v;
}

// ---------------- pass 1: rowsum over src (atomic) + dst histogram w/ rank ----------------
// 1 edge/thread; floor = memory-side atomic RMW throughput (~17G/s), measured r5/r6.

__global__ void k_pass1(const int* __restrict__ src, const int* __restrict__ dst,
                        const float* __restrict__ w, float* __restrict__ rowsum,
                        int* __restrict__ cnt, int* __restrict__ rank, int E) {
    int e = blockIdx.x * 256 + threadIdx.x;
    if (e >= E) return;
    atomicAdd(&rowsum[src[e]], w[e]);
    rank[e] = atomicAdd(&cnt[dst[e]], 1);
}

// ---------------- prefix scan (3-phase) over cnt[N] -> start[N+1] ----------------

__global__ void k_chunk_sum(const int* __restrict__ cnt, int* __restrict__ partial, int n) {
    __shared__ int sdata[256];
    int b = blockIdx.x;
    int base = b * SCAN_CHUNK;
    int s = 0;
    for (int i = threadIdx.x; i < SCAN_CHUNK; i += 256) {
        int idx = base + i;
        s += (idx < n) ? cnt[idx] : 0;
    }
    sdata[threadIdx.x] = s;
    __syncthreads();
    for (int off = 128; off > 0; off >>= 1) {
        if (threadIdx.x < off) sdata[threadIdx.x] += sdata[threadIdx.x + off];
        __syncthreads();
    }
    if (threadIdx.x == 0) partial[b] = sdata[0];
}

__global__ void k_scan_partial(int* __restrict__ partial, int nchunks) {
    if (blockIdx.x == 0 && threadIdx.x == 0) {
        int run = 0;
        for (int i = 0; i < nchunks; i++) { int v = partial[i]; partial[i] = run; run += v; }
    }
}

__global__ void k_chunk_scan(const int* __restrict__ cnt, const int* __restrict__ partial,
                             int* __restrict__ start, int n, int total) {
    __shared__ int sdata[256];
    int b = blockIdx.x;
    int base = b * SCAN_CHUNK;
    int t = threadIdx.x;
    int loc[8];
    int s = 0;
    int tb = base + t * 8;
    #pragma unroll
    for (int j = 0; j < 8; j++) {
        int idx = tb + j;
        int v = (idx < n) ? cnt[idx] : 0;
        loc[j] = s;
        s += v;
    }
    sdata[t] = s;
    __syncthreads();
    for (int off = 1; off < 256; off <<= 1) {
        int v = (t >= off) ? sdata[t - off] : 0;
        __syncthreads();
        sdata[t] += v;
        __syncthreads();
    }
    int texcl = (t == 0) ? 0 : sdata[t - 1];
    int offb = partial[b];
    #pragma unroll
    for (int j = 0; j < 8; j++) {
        int idx = tb + j;
        if (idx < n) start[idx] = offb + texcl + loc[j];
    }
    if (b == gridDim.x - 1 && t == 255) start[n] = total;
}

// ---------------- scatter (NO atomics): compute w_hat, place at start[d]+rank[e] ----------------

__global__ void k_scatter2(const int* __restrict__ src, const int* __restrict__ dst,
                           const float* __restrict__ w, const float* __restrict__ rowsum,
                           const int* __restrict__ start, const int* __restrict__ rank,
                           int2* __restrict__ csr, int E) {
    int e = blockIdx.x * 256 + threadIdx.x;
    if (e >= E) return;
    int s = src[e], d = dst[e];
    float rs = rowsum[s], rd = rowsum[d];
    float wh = w[e] * (rs > 0.f ? 1.f / rs : 0.f) * (rd > 0.f ? 1.f / rd : 0.f);
    int idx = start[d] + rank[e];
    csr[idx] = make_int2(s, __float_as_int(wh));
}

// ---------------- deg via contiguous segment gather (no atomics) -> dinv ----------------

__global__ void k_deg_dinv(const int2* __restrict__ csr, const int* __restrict__ start,
                           float* __restrict__ dinv, int N) {
    int n = blockIdx.x * 256 + threadIdx.x;
    if (n >= N) return;
    int s0 = start[n], s1 = start[n + 1];
    float s = 0.f;
    for (int i = s0; i < s1; i++) s += __int_as_float(csr[i].y);
    dinv[n] = s > 0.f ? rsqrtf(s) : 0.f;
}

// ---------------- MFMA GEMM: Yb[N,128](bf16) = X[N,128] @ W[128,128] ----------------
// 256 thr = 4 waves, 64 rows/block. Wt pre-swizzled bf16 in GLOBAL (k_wprep);
// staging = linear uint4 copy. X tile XOR-swizzled -> conflict-free ds_read_b128.
// DO_NORM=1 (layer 1): X read f32 from feat, row-normalized in registers.
// DO_NORM=0: X read bf16 (in-place safe: block stages its rows pre-write).

#define GR 64

template<int DO_NORM>
__global__ __launch_bounds__(256) void k_gemm_mfma(const float* __restrict__ Xf32,
                                                   const unsigned short* __restrict__ Xb,
                                                   const unsigned short* __restrict__ Wtg,
                                                   unsigned short* __restrict__ Yb, int nrows) {
    __shared__ unsigned short Wt[128 * 128];   // 32KB: [col][k] bf16, swizzled
    __shared__ unsigned short Xs[GR * 128];    // 16KB: [row][k] bf16, swizzled
    int t = threadIdx.x;
    int rowbase = blockIdx.x * GR;

    // stage W: linear copy of pre-swizzled global layout (8 x uint4 per thread)
    {
        const uint4* Wg = (const uint4*)Wtg;
        uint4* Wl = (uint4*)Wt;
        #pragma unroll
        for (int i = 0; i < 8; i++) Wl[t + i * 256] = Wg[t + i * 256];
    }

    if (DO_NORM) {
        // 4 threads per row; thread q owns float4s {q, q+4, ..., q+28} (coalesced per k)
        int r = t >> 2, q = t & 3;
        int row = rowbase + r;
        const float4* Xr = (const float4*)(Xf32 + (size_t)row * 128);
        float4 v[8];
        float s = 0.f;
        #pragma unroll
        for (int k = 0; k < 8; k++) {
            float4 x = make_float4(0.f, 0.f, 0.f, 0.f);
            if (row < nrows) x = Xr[q + k * 4];
            v[k] = x;
            s += x.x + x.y + x.z + x.w;
        }
        s += __shfl_down(s, 2, 4);
        s += __shfl_down(s, 1, 4);
        float tot = __shfl(s, 0, 4);
        float inv = tot > 0.f ? 1.f / tot : 0.f;
        int sw = (r & 7) << 4;
        #pragma unroll
        for (int k = 0; k < 8; k++) {
            int gidx = q + k * 4;                  // float4 index 0..31 within row
            ushort4 h;
            h.x = f2bf(v[k].x * inv); h.y = f2bf(v[k].y * inv);
            h.z = f2bf(v[k].z * inv); h.w = f2bf(v[k].w * inv);
            *(ushort4*)((char*)Xs + r * 256 + ((gidx * 8) ^ sw)) = h;
        }
    } else {
        for (int i = t; i < GR * 16; i += 256) {
            int r = i >> 4, c = i & 15;
            uint4 vv = {0u, 0u, 0u, 0u};
            int row = rowbase + r;
            if (row < nrows) vv = *(const uint4*)(Xb + (size_t)row * 128 + c * 8);
            int byte = r * 256 + ((c * 16) ^ ((r & 7) << 4));
            *(uint4*)((char*)Xs + byte) = vv;
        }
    }
    __syncthreads();

    int w = t >> 6, l = t & 63;
    int r0 = w * 16;
    int lr = l & 15, lg = l >> 4;

    short8 a[4];
    {
        int row = r0 + lr;
        const char* rp = (const char*)Xs + row * 256;
        int sw = (row & 7) << 4;
        #pragma unroll
        for (int s = 0; s < 4; s++)
            a[s] = *(const short8*)(rp + ((s * 64 + lg * 16) ^ sw));
    }

    f32x4 acc[8];
    #pragma unroll
    for (int ct = 0; ct < 8; ct++) {
        f32x4 c = {0.f, 0.f, 0.f, 0.f};
        int col = ct * 16 + lr;
        const char* cp = (const char*)Wt + col * 256;
        int sw = (col & 7) << 4;
        #pragma unroll
        for (int s = 0; s < 4; s++) {
            short8 b = *(const short8*)(cp + ((s * 64 + lg * 16) ^ sw));
            c = __builtin_amdgcn_mfma_f32_16x16x32_bf16(a[s], b, c, 0, 0, 0);
        }
        acc[ct] = c;
    }

    #pragma unroll
    for (int j = 0; j < 4; j++) {
        int row = rowbase + r0 + lg * 4 + j;
        if (row < nrows) {
            #pragma unroll
            for (int ct = 0; ct < 8; ct++)
                Yb[(size_t)row * 128 + ct * 16 + lr] = f2bf(acc[ct][j]);
        }
    }
}

// ---------------- aggregation (bf16 gather, f32 accum) ----------------
// 4 nodes/wave: 16-lane groups; lane owns cols 8l..8l+7 (one uint4 = 8 bf16/row).
// NORM=1 (layer 1): csr holds raw w_hat; apply dinv[src]*dinv[dst] on the fly and
// write the normalized value back for layers 2/3 (each entry owned by one lane).
// FINAL=0: leaky + bf16 out ; FINAL=1: no act + f32 out (d_out).

__device__ __forceinline__ void fma8(float* acc, float n, uint4 v) {
    acc[0] += n * __uint_as_float(v.x << 16);
    acc[1] += n * __uint_as_float(v.x & 0xffff0000u);
    acc[2] += n * __uint_as_float(v.y << 16);
    acc[3] += n * __uint_as_float(v.y & 0xffff0000u);
    acc[4] += n * __uint_as_float(v.z << 16);
    acc[5] += n * __uint_as_float(v.z & 0xffff0000u);
    acc[6] += n * __uint_as_float(v.w << 16);
    acc[7] += n * __uint_as_float(v.w & 0xffff0000u);
}

template<int NORM, int FINAL>
__global__ void k_agg(const unsigned short* __restrict__ Yb, int2* __restrict__ csr,
                      const int* __restrict__ start, const float* __restrict__ dinv,
                      const float* __restrict__ bias,
                      unsigned short* __restrict__ OutB, float* __restrict__ OutF, int N) {
    int wid = (blockIdx.x * blockDim.x + threadIdx.x) >> 6;
    int lane = threadIdx.x & 63;
    int g = lane >> 4;
    int l = lane & 15;
    int node = wid * 4 + g;
    bool valid = node < N;
    int s0 = valid ? start[node] : 0;
    int s1 = valid ? start[node + 1] : 0;
    int cnt = s1 - s0;
    float ddst = 0.f;
    if (NORM) ddst = valid ? dinv[node] : 0.f;

    float acc[8] = {};
    const uint4* Y4 = (const uint4*)Yb;          // row = 16 uint4

    for (int base = 0; base < cnt; base += 16) {
        int rem = cnt - base; if (rem > 16) rem = 16;
        int eidx = s0 + base + l;
        int2 pr = (l < rem) ? csr[eidx] : make_int2(0, 0);
        int  sj = pr.x;
        float nj = __int_as_float(pr.y);
        if (NORM) {
            nj = nj * dinv[sj] * ddst;               // l>=rem: nj=0 stays 0
            if (l < rem) csr[eidx] = make_int2(sj, __float_as_int(nj));
        }
        int j = 0;
        for (; j + 8 <= rem; j += 8) {
            int   i0 = __shfl(sj, j + 0, 16), i1 = __shfl(sj, j + 1, 16);
            int   i2 = __shfl(sj, j + 2, 16), i3 = __shfl(sj, j + 3, 16);
            int   i4 = __shfl(sj, j + 4, 16), i5 = __shfl(sj, j + 5, 16);
            int   i6 = __shfl(sj, j + 6, 16), i7 = __shfl(sj, j + 7, 16);
            float n0 = __shfl(nj, j + 0, 16), n1 = __shfl(nj, j + 1, 16);
            float n2 = __shfl(nj, j + 2, 16), n3 = __shfl(nj, j + 3, 16);
            float n4 = __shfl(nj, j + 4, 16), n5 = __shfl(nj, j + 5, 16);
            float n6 = __shfl(nj, j + 6, 16), n7 = __shfl(nj, j + 7, 16);
            uint4 v0 = Y4[(size_t)i0 * 16 + l];
            uint4 v1 = Y4[(size_t)i1 * 16 + l];
            uint4 v2 = Y4[(size_t)i2 * 16 + l];
            uint4 v3 = Y4[(size_t)i3 * 16 + l];
            uint4 v4 = Y4[(size_t)i4 * 16 + l];
            uint4 v5 = Y4[(size_t)i5 * 16 + l];
            uint4 v6 = Y4[(size_t)i6 * 16 + l];
            uint4 v7 = Y4[(size_t)i7 * 16 + l];
            fma8(acc, n0, v0); fma8(acc, n1, v1);
            fma8(acc, n2, v2); fma8(acc, n3, v3);
            fma8(acc, n4, v4); fma8(acc, n5, v5);
            fma8(acc, n6, v6); fma8(acc, n7, v7);
        }
        for (; j + 4 <= rem; j += 4) {
            int   i0 = __shfl(sj, j + 0, 16), i1 = __shfl(sj, j + 1, 16);
            int   i2 = __shfl(sj, j + 2, 16), i3 = __shfl(sj, j + 3, 16);
            float n0 = __shfl(nj, j + 0, 16), n1 = __shfl(nj, j + 1, 16);
            float n2 = __shfl(nj, j + 2, 16), n3 = __shfl(nj, j + 3, 16);
            uint4 v0 = Y4[(size_t)i0 * 16 + l];
            uint4 v1 = Y4[(size_t)i1 * 16 + l];
            uint4 v2 = Y4[(size_t)i2 * 16 + l];
            uint4 v3 = Y4[(size_t)i3 * 16 + l];
            fma8(acc, n0, v0); fma8(acc, n1, v1);
            fma8(acc, n2, v2); fma8(acc, n3, v3);
        }
        for (; j < rem; j++) {
            int   i0 = __shfl(sj, j, 16);
            float n0 = __shfl(nj, j, 16);
            uint4 v0 = Y4[(size_t)i0 * 16 + l];
            fma8(acc, n0, v0);
        }
    }

    if (!valid) return;
    float4 ba = ((const float4*)bias)[l * 2];
    float4 bb = ((const float4*)bias)[l * 2 + 1];
    float o[8];
    o[0] = acc[0] + ba.x; o[1] = acc[1] + ba.y; o[2] = acc[2] + ba.z; o[3] = acc[3] + ba.w;
    o[4] = acc[4] + bb.x; o[5] = acc[5] + bb.y; o[6] = acc[6] + bb.z; o[7] = acc[7] + bb.w;
    if (FINAL) {
        float4 w0 = {o[0], o[1], o[2], o[3]};
        float4 w1 = {o[4], o[5], o[6], o[7]};
        ((float4*)OutF)[(size_t)node * 32 + l * 2] = w0;
        ((float4*)OutF)[(size_t)node * 32 + l * 2 + 1] = w1;
    } else {
        #pragma unroll
        for (int k = 0; k < 8; k++) o[k] = o[k] > 0.f ? o[k] : LEAKY * o[k];
        uint4 ov;
        ov.x = (unsigned)f2bf(o[0]) | ((unsigned)f2bf(o[1]) << 16);
        ov.y = (unsigned)f2bf(o[2]) | ((unsigned)f2bf(o[3]) << 16);
        ov.z = (unsigned)f2bf(o[4]) | ((unsigned)f2bf(o[5]) << 16);
        ov.w = (unsigned)f2bf(o[6]) | ((unsigned)f2bf(o[7]) << 16);
        ((uint4*)OutB)[(size_t)node * 16 + l] = ov;
    }
}

// ---------------- launch ----------------

extern "C" void kernel_launch(void* const* d_in, const int* in_sizes, int n_in,
                              void* d_out, int out_size, void* d_ws, size_t ws_size,
                              hipStream_t stream) {
    const float* feat = (const float*)d_in[0];
    const int*   eidx = (const int*)d_in[1];
    const float* ew   = (const float*)d_in[2];
    const float* W1   = (const float*)d_in[3];
    const float* b1   = (const float*)d_in[4];
    const float* W2   = (const float*)d_in[5];
    const float* b2   = (const float*)d_in[6];
    const float* W3   = (const float*)d_in[7];
    const float* b3   = (const float*)d_in[8];

    const int N = in_sizes[0] / D;   // 50000
    const int E = in_sizes[2];       // 600000
    const int* src = eidx;
    const int* dst = eidx + E;

    // workspace layout (4B units)
    size_t off = 0;
    char* base = (char*)d_ws;
    auto alloc4 = [&](size_t elems) -> void* {
        void* p = base + off * 4;
        off += (elems + 3) & ~(size_t)3;
        return p;
    };
    float* rowsum = (float*)alloc4(N);      // zeroed
    int*   cnt    = (int*)  alloc4(N);      // zeroed (contiguous with rowsum)
    char*  zero_end = base + off * 4;
    int*   start  = (int*)  alloc4(N + 1);
    float* dinv   = (float*)alloc4(N);
    int*   partial= (int*)  alloc4(64);
    int*   rank   = (int*)  alloc4(E);
    int2*  csr    = (int2*) alloc4((size_t)E * 2);
    unsigned short* wtg = (unsigned short*)alloc4(24576);          // 3 x 128x128 bf16, pre-swizzled
    unsigned short* xb  = (unsigned short*)alloc4((size_t)N * 64); // N x 128 bf16
    unsigned short* yb  = (unsigned short*)alloc4((size_t)N * 64);
    float* outp = (float*)d_out;

    hipMemsetAsync(rowsum, 0, (size_t)(zero_end - (char*)rowsum), stream);

    int eblocks = (E + 255) / 256;
    int nchunks = (N + SCAN_CHUNK - 1) / SCAN_CHUNK;
    int nblocks = (N + 255) / 256;
    int ablocks = (((N + 3) / 4) * 64 + 255) / 256; // k_agg: 4 nodes per wave
    int gblocks = (N + GR - 1) / GR;

    k_wprep<<<24, 256, 0, stream>>>(W1, W2, W3, wtg);
    k_pass1<<<eblocks, 256, 0, stream>>>(src, dst, ew, rowsum, cnt, rank, E);

    k_chunk_sum<<<nchunks, 256, 0, stream>>>(cnt, partial, N);
    k_scan_partial<<<1, 64, 0, stream>>>(partial, nchunks);
    k_chunk_scan<<<nchunks, 256, 0, stream>>>(cnt, partial, start, N, E);

    k_scatter2<<<eblocks, 256, 0, stream>>>(src, dst, ew, rowsum, start, rank, csr, E);
    k_deg_dinv<<<nblocks, 256, 0, stream>>>(csr, start, dinv, N);

    // L1: gemm feat->xb (fused row-normalize), agg xb->yb (fused csr-norm, leaky, bf16)
    k_gemm_mfma<1><<<gblocks, 256, 0, stream>>>(feat, nullptr, wtg, xb, N);
    k_agg<1, 0><<<ablocks, 256, 0, stream>>>(xb, csr, start, dinv, b1, yb, nullptr, N);
    // L2: gemm yb->yb (in-place), agg yb->xb (leaky, bf16)
    k_gemm_mfma<0><<<gblocks, 256, 0, stream>>>(nullptr, yb, wtg + 16384, yb, N);
    k_agg<0, 0><<<ablocks, 256, 0, stream>>>(yb, csr, start, nullptr, b2, xb, nullptr, N);
    // L3: gemm xb->xb (in-place), agg xb->d_out (no act, f32)
    k_gemm_mfma<0><<<gblocks, 256, 0, stream>>>(nullptr, xb, wtg + 32768, xb, N);
    k_agg<0, 1><<<ablocks, 256, 0, stream>>>(xb, csr, start, nullptr, b3, nullptr, outp, N);
}